// Round 6
// baseline (1518.221 us; speedup 1.0000x reference)
//
#include <hip/hip_runtime.h>
#include <stdint.h>

// ---------------------------------------------------------------------------
// Dueling-DQN forward on MI355X. Round 6: conv_rr gets (a) SLOTB bank-pad so
// row-crossing reads are bank-contiguous (conflict-free), (b) 4-set / 3-ahead
// register pipeline for A+B fragments, (c) s_setprio around MFMA clusters.
// ---------------------------------------------------------------------------

using bf16_t = __bf16;
using bf16x8 = __attribute__((ext_vector_type(8))) __bf16;
using bf16x4 = __attribute__((ext_vector_type(4))) __bf16;
using f32x4  = __attribute__((ext_vector_type(4))) float;
using f32x16 = __attribute__((ext_vector_type(16))) float;

__device__ __forceinline__ f32x4 mfma16(bf16x8 a, bf16x8 b, f32x4 c) {
    return __builtin_amdgcn_mfma_f32_16x16x32_bf16(a, b, c, 0, 0, 0);
}
__device__ __forceinline__ f32x16 mfma32(bf16x8 a, bf16x8 b, f32x16 c) {
    return __builtin_amdgcn_mfma_f32_32x32x16_bf16(a, b, c, 0, 0, 0);
}

template<bool A16>
__device__ __forceinline__ bf16x8 load_frag(const bf16_t* p) {
    if constexpr (A16) {
        return *reinterpret_cast<const bf16x8*>(p);
    } else {
        union { bf16x8 v; uint64_t u[2]; } r;
        r.u[0] = *reinterpret_cast<const uint64_t*>(p);
        r.u[1] = *reinterpret_cast<const uint64_t*>(p + 4);
        return r.v;
    }
}

// ---------------------------------------------------------------------------
// Generic pack: dst[cout][khw][cin] = (bf16)src[cout][cin][khw]
// ---------------------------------------------------------------------------
template<int CIN>
__global__ void pack_w(const float* __restrict__ src, bf16_t* __restrict__ dst,
                       int COUT, int KK) {
    int total = COUT * KK;
    for (int t = blockIdx.x * blockDim.x + threadIdx.x; t < total;
         t += gridDim.x * blockDim.x) {
        int cout = t / KK;
        int khw  = t - cout * KK;
        alignas(16) bf16_t tmp[CIN];
        #pragma unroll
        for (int c = 0; c < CIN; ++c)
            tmp[c] = (bf16_t)src[((size_t)cout * CIN + c) * KK + khw];
        bf16_t* d = dst + (size_t)t * CIN;
        if constexpr (CIN == 1) {
            d[0] = tmp[0];
        } else if constexpr (CIN == 4) {
            *reinterpret_cast<uint2*>(d) = *reinterpret_cast<const uint2*>(tmp);
        } else {
            #pragma unroll
            for (int c = 0; c < CIN; c += 8)
                *reinterpret_cast<uint4*>(d + c) =
                    *reinterpret_cast<const uint4*>(tmp + c);
        }
    }
}

// ---------------------------------------------------------------------------
// A-fragment pack for 32x32x16 MFMA conv: frag f = (kh*S + s)*NT + n holds
// couts n*32+(l&31); k = s*16 + (l>>5)*8 + e; k -> (kw = k/CIN, cin = k%CIN).
// Source OIHW [COUT][CIN][K][K]. dst[f*512 + lane*8 + e], 1KB per frag.
// ---------------------------------------------------------------------------
template<int CIN, int COUT, int K>
__global__ void pack_wA(const float* __restrict__ src, bf16_t* __restrict__ dst) {
    constexpr int S  = K * CIN / 16;
    constexpr int NT = COUT / 32;
    int t = blockIdx.x * 256 + threadIdx.x;
    int l  = t & 63;
    int f  = t >> 6;
    int n  = f % NT;
    int fs = f / NT;
    int s  = fs % S;
    int kh = fs / S;
    if (kh >= K) return;
    int cout = n * 32 + (l & 31);
    int k0   = s * 16 + (l >> 5) * 8;
    alignas(16) bf16_t tmp[8];
    #pragma unroll
    for (int e = 0; e < 8; ++e) {
        int k   = k0 + e;
        int kw  = k / CIN;
        int cin = k % CIN;
        tmp[e] = (bf16_t)src[(((size_t)cout * CIN + cin) * K + kh) * K + kw];
    }
    *reinterpret_cast<uint4*>(dst + (size_t)t * 8) =
        *reinterpret_cast<const uint4*>(tmp);
}

// scalar = relu(fc1(concat(g[0],v[0]))[30])
__global__ void fc1_scalar(const float* __restrict__ g, const float* __restrict__ v,
                           const float* __restrict__ w, const float* __restrict__ b,
                           float* __restrict__ outp) {
    if (threadIdx.x == 0 && blockIdx.x == 0) {
        float s = b[30] + g[0] * w[120] + g[1] * w[121] + v[0] * w[122] + v[1] * w[123];
        *outp = s > 0.f ? s : 0.f;
    }
}

// ---------------------------------------------------------------------------
// Rolling-row LDS implicit-GEMM conv, 32x32x16 MFMA.
// TR layout (CIN>=16): chunk-planes lds[slot][c][q]; B-read for k-step s:
// plane (s%SPP)*2+h, q=ow+s/SPP -> lane-contiguous 16B.
// SLOTB padded so SLOTB = 16*OW (mod 128): row-crossing reads stay
// bank-contiguous. 4-set/3-ahead register pipeline; setprio around MFMA.
// ---------------------------------------------------------------------------
template<int CIN, int COUT, int W, int K, int OW, int WMT, int NSLOT,
         int ADD_SCALAR>
__global__ __launch_bounds__(256, 2) void conv_rr(
    const bf16_t* __restrict__ in, const bf16_t* __restrict__ wA,
    const float* __restrict__ bias, bf16_t* __restrict__ out,
    const float* __restrict__ scal) {
    constexpr int  P     = OW * OW;
    constexpr int  PIXB  = CIN * 2;
    constexpr int  ROWB  = W * PIXB;
    constexpr bool TR    = (CIN >= 16);
    constexpr int  NCH   = TR ? PIXB / 16 : 1;      // chunk-planes per pixel
    constexpr int  SPP   = TR ? NCH / 2 : 1;        // k-steps per pixel
    constexpr int  PS    = TR ? (W + 1) * 16 : 0;   // plane stride (padded)
    constexpr int  SLOTB0 = TR ? NCH * PS : ROWB;
    constexpr int  PADB  = TR ? ((16 * OW - SLOTB0) % 128 + 128) % 128 : 0;
    constexpr int  SLOTB = SLOTB0 + PADB;           // bytes per row-slot
    constexpr int  LDSB  = NSLOT * SLOTB;
    constexpr int  S     = K * CIN / 16;            // divisible by 4 everywhere
    constexpr int  NT    = COUT / 32;
    constexpr int  BPX   = WMT * 32 * 4;
    constexpr int  CH    = ROWB / 16;               // 16B chunks per row
    constexpr int  NLD   = (CH + 255) / 256;
    __shared__ __align__(16) char smem[LDSB];

    const int tid  = threadIdx.x;
    const int wave = tid >> 6, lane = tid & 63;
    const int l31  = lane & 31, h = lane >> 5;
    const int img  = blockIdx.z;
    const int p0   = blockIdx.x * BPX;

    const char* inb = (const char*)(in + (size_t)img * ((size_t)W * W * CIN));

    const int r0 = p0 / OW;
    int plast = p0 + BPX - 1; if (plast > P - 1) plast = P - 1;
    const int r1 = plast / OW;

    // staging chunk->LDS offset for this thread (same map for all rows)
    int woff[NLD];
    #pragma unroll
    for (int i = 0; i < NLD; ++i) {
        int c = i * 256 + tid;
        if (c < CH) woff[i] = TR ? (c % NCH) * PS + (c / NCH) * 16 : c * 16;
        else        woff[i] = 0;
    }

    int pix[WMT], ldsadr[WMT];
    #pragma unroll
    for (int m = 0; m < WMT; ++m) {
        int p  = p0 + (wave * WMT + m) * 32 + l31;
        pix[m] = p;
        int pc = p < P ? p : P - 1;
        int oh = pc / OW;
        int ow = pc - oh * OW;
        ldsadr[m] = (oh % NSLOT) * SLOTB +
                    (TR ? ow * 16 + h * PS : ow * PIXB + h * 16);
    }

    // prologue: stage rows r0..r1
    for (int r = r0; r <= r1; ++r) {
        const char* g = inb + (size_t)r * ROWB;
        int base = (r % NSLOT) * SLOTB;
        for (int c = tid; c < CH; c += 256) {
            bf16x8 v = *reinterpret_cast<const bf16x8*>(g + c * 16);
            int off = TR ? (c % NCH) * PS + (c / NCH) * 16 : c * 16;
            *reinterpret_cast<bf16x8*>(smem + base + off) = v;
        }
    }
    __syncthreads();

    f32x16 acc[WMT][NT] = {};

    int wsl = (r1 + 1) % NSLOT;
    const char* gpre = inb + (size_t)(r1 + 1) * ROWB;
    const bf16_t* wl = wA + lane * 8;

    for (int kh = 0; kh < K; ++kh) {
        bf16x8 stv[NLD];
        const bool pf = kh < K - 1;
        if (pf) {                                    // T14: issue early
            #pragma unroll
            for (int i = 0; i < NLD; ++i) {
                int c = i * 256 + tid;
                if (c < CH) stv[i] = *reinterpret_cast<const bf16x8*>(gpre + c * 16);
            }
        }
        const bf16_t* ap = wl + (size_t)kh * (S * NT * 512);

        // ---- 4-set, 3-ahead software pipeline over s ----
        bf16x8 bS0[WMT], bS1[WMT], bS2[WMT], bS3[WMT];
        bf16x8 aS0[NT],  aS1[NT],  aS2[NT],  aS3[NT];

#define LOADSET(BS, AS, SIDX)                                               \
        {                                                                   \
            const int _s = (SIDX);                                          \
            _Pragma("unroll")                                               \
            for (int m = 0; m < WMT; ++m) {                                 \
                int a = TR ? ldsadr[m] + (_s % SPP) * (2 * PS) + (_s / SPP) * 16 \
                           : ldsadr[m] + _s * 32;                           \
                BS[m] = *reinterpret_cast<const bf16x8*>(smem + a);         \
            }                                                               \
            _Pragma("unroll")                                               \
            for (int n = 0; n < NT; ++n)                                    \
                AS[n] = *reinterpret_cast<const bf16x8*>(ap + (_s * NT + n) * 512); \
        }
#define MFMASET(BS, AS)                                                     \
        {                                                                   \
            __builtin_amdgcn_s_setprio(1);                                  \
            _Pragma("unroll")                                               \
            for (int m = 0; m < WMT; ++m)                                   \
                _Pragma("unroll")                                           \
                for (int n = 0; n < NT; ++n)                                \
                    acc[m][n] = mfma32(AS[n], BS[m], acc[m][n]);            \
            __builtin_amdgcn_s_setprio(0);                                  \
        }

        LOADSET(bS0, aS0, 0)
        LOADSET(bS1, aS1, 1)
        LOADSET(bS2, aS2, 2)
        for (int sb = 0; sb + 8 <= S; sb += 4) {
            MFMASET(bS0, aS0)  LOADSET(bS3, aS3, sb + 3)
            MFMASET(bS1, aS1)  LOADSET(bS0, aS0, sb + 4)
            MFMASET(bS2, aS2)  LOADSET(bS1, aS1, sb + 5)
            MFMASET(bS3, aS3)  LOADSET(bS2, aS2, sb + 6)
        }
        // drain group (positions S-4..S-1; only first prefetches S-1)
        MFMASET(bS0, aS0)  LOADSET(bS3, aS3, S - 1)
        MFMASET(bS1, aS1)
        MFMASET(bS2, aS2)
        MFMASET(bS3, aS3)
#undef LOADSET
#undef MFMASET

        if (pf) {                                    // write-late
            int wb0 = wsl * SLOTB;
            #pragma unroll
            for (int i = 0; i < NLD; ++i) {
                int c = i * 256 + tid;
                if (c < CH)
                    *reinterpret_cast<bf16x8*>(smem + wb0 + woff[i]) = stv[i];
            }
            gpre += ROWB;
            wsl = (wsl + 1 == NSLOT) ? 0 : wsl + 1;
        }
        __syncthreads();
        #pragma unroll
        for (int m = 0; m < WMT; ++m) {
            int a2 = ldsadr[m] + SLOTB;
            ldsadr[m] = a2 >= LDSB ? a2 - LDSB : a2;
        }
    }

    float sc = 0.f;
    if constexpr (ADD_SCALAR) sc = *scal;
    bf16_t* outb = out + (size_t)img * ((size_t)P * COUT);
    #pragma unroll
    for (int m = 0; m < WMT; ++m) {
        if (pix[m] < P) {
            #pragma unroll
            for (int n = 0; n < NT; ++n) {
                #pragma unroll
                for (int rg = 0; rg < 4; ++rg) {
                    int cb = n * 32 + rg * 8 + h * 4;
                    f32x4 bv = *reinterpret_cast<const f32x4*>(bias + cb);
                    union { bf16x4 v; uint2 u; } o;
                    #pragma unroll
                    for (int j = 0; j < 4; ++j) {
                        float x = acc[m][n][rg * 4 + j] + bv[j];
                        x = x > 0.f ? x : 0.f;
                        x += sc;
                        o.v[j] = (bf16_t)x;
                    }
                    *reinterpret_cast<uint2*>(outb + (size_t)pix[m] * COUT + cb) = o.u;
                }
            }
        }
    }
}

// ---------------------------------------------------------------------------
// Generic implicit-GEMM conv (16x16x32) via global loads — used for conv4c.
// ---------------------------------------------------------------------------
template<int CIN, int COUT, int W, int K, int OW, int NBLK, int WMT,
         int ADD_SCALAR, bool A16>
__global__ __launch_bounds__(256, 2) void conv_mfma(
    const bf16_t* __restrict__ in, const bf16_t* __restrict__ wp,
    const float* __restrict__ bias, bf16_t* __restrict__ out,
    const float* __restrict__ scal) {
    constexpr int P    = OW * OW;
    constexpr int KCIN = K * CIN;
    constexpr int KTOT = K * KCIN;
    constexpr int RS   = KCIN / 32;
    constexpr int NT   = NBLK / 16;
    constexpr int BMT  = WMT * 4;

    const int b     = blockIdx.z;
    const int cout0 = blockIdx.y * NBLK;
    const int wave  = threadIdx.x >> 6;
    const int lane  = threadIdx.x & 63;
    const int l15   = lane & 15;
    const int l4    = lane >> 4;
    const int mt0   = blockIdx.x * BMT + wave * WMT;

    const bf16_t* inb = in + (size_t)b * (W * W * CIN);

    int      pix[WMT];
    uint32_t pb[WMT];
    #pragma unroll
    for (int m = 0; m < WMT; ++m) {
        int p  = (mt0 + m) * 16 + l15;
        pix[m] = p;
        int pc = p < P ? p : P - 1;
        int oh = pc / OW;
        int ow = pc - oh * OW;
        pb[m]  = (uint32_t)(oh * W + ow) * CIN;
    }
    uint32_t wb[NT];
    #pragma unroll
    for (int n = 0; n < NT; ++n)
        wb[n] = (uint32_t)(cout0 + n * 16 + l15) * KTOT + (uint32_t)l4 * 8u;

    f32x4 acc[WMT][NT];
    #pragma unroll
    for (int m = 0; m < WMT; ++m)
        #pragma unroll
        for (int n = 0; n < NT; ++n)
            acc[m][n] = f32x4{0.f, 0.f, 0.f, 0.f};

    uint32_t bofs = (uint32_t)l4 * 8u;
    for (int kh = 0; kh < K; ++kh) {
        #pragma unroll
        for (int s = 0; s < RS; ++s) {
            bf16x8 af[NT];
            #pragma unroll
            for (int n = 0; n < NT; ++n)
                af[n] = load_frag<true>(wp + wb[n] + kh * KCIN + s * 32);
            #pragma unroll
            for (int m = 0; m < WMT; ++m) {
                bf16x8 bfr = load_frag<A16>(inb + pb[m] + bofs + s * 32);
                #pragma unroll
                for (int n = 0; n < NT; ++n)
                    acc[m][n] = mfma16(af[n], bfr, acc[m][n]);
            }
        }
        bofs += (uint32_t)(W * CIN);
    }

    float sc = 0.f;
    if constexpr (ADD_SCALAR) sc = *scal;
    bf16_t* outb = out + (size_t)b * P * COUT;
    #pragma unroll
    for (int n = 0; n < NT; ++n) {
        const int cb = cout0 + n * 16 + l4 * 4;
        f32x4 bv = *reinterpret_cast<const f32x4*>(bias + cb);
        #pragma unroll
        for (int m = 0; m < WMT; ++m) {
            if (pix[m] < P) {
                f32x4 v = acc[m][n];
                union { bf16x4 h; uint2 u; } st;
                #pragma unroll
                for (int r = 0; r < 4; ++r) {
                    float x = v[r] + bv[r];
                    x = x > 0.f ? x : 0.f;
                    x += sc;
                    st.h[r] = (bf16_t)x;
                }
                *reinterpret_cast<uint2*>(outb + (size_t)pix[m] * COUT + cb) = st.u;
            }
        }
    }
}

// ---------------------------------------------------------------------------
// fc2: [128,6400]x[512,6400]^T, K-split x4 into f32 partials.
// ---------------------------------------------------------------------------
__global__ __launch_bounds__(256, 2) void fc2_kernel(
    const bf16_t* __restrict__ x, const bf16_t* __restrict__ w,
    float* __restrict__ part) {
    const int nb = blockIdx.x, kc = blockIdx.y;
    const int wave = threadIdx.x >> 6, lane = threadIdx.x & 63;
    const int l15 = lane & 15, l4 = lane >> 4;
    const int wm = wave & 1, wn = wave >> 1;

    f32x4 acc[4][2];
    #pragma unroll
    for (int m = 0; m < 4; ++m)
        #pragma unroll
        for (int n = 0; n < 2; ++n) acc[m][n] = f32x4{0.f, 0.f, 0.f, 0.f};

    uint32_t xb[4], wbf[2];
    #pragma unroll
    for (int m = 0; m < 4; ++m)
        xb[m] = (uint32_t)(16 * (wm * 4 + m) + l15) * 6400u + kc * 1600u + l4 * 8u;
    #pragma unroll
    for (int n = 0; n < 2; ++n)
        wbf[n] = (uint32_t)(nb * 64 + wn * 32 + n * 16 + l15) * 6400u + kc * 1600u + l4 * 8u;

    for (int s = 0; s < 50; ++s) {
        bf16x8 af[2];
        #pragma unroll
        for (int n = 0; n < 2; ++n)
            af[n] = load_frag<true>(w + wbf[n] + s * 32);
        #pragma unroll
        for (int m = 0; m < 4; ++m) {
            bf16x8 bfr = load_frag<true>(x + xb[m] + s * 32);
            #pragma unroll
            for (int n = 0; n < 2; ++n)
                acc[m][n] = mfma16(af[n], bfr, acc[m][n]);
        }
    }
    #pragma unroll
    for (int m = 0; m < 4; ++m) {
        int bcol = 16 * (wm * 4 + m) + l15;
        #pragma unroll
        for (int n = 0; n < 2; ++n) {
            int cf = nb * 64 + wn * 32 + n * 16 + l4 * 4;
            *reinterpret_cast<f32x4*>(part + ((size_t)kc * 128 + bcol) * 512 + cf) =
                acc[m][n];
        }
    }
}

__global__ void fc2_reduce(const float* __restrict__ part,
                           const float* __restrict__ bias,
                           bf16_t* __restrict__ xo) {
    int t = blockIdx.x * 256 + threadIdx.x;
    if (t < 128 * 512) {
        int b = t >> 9, co = t & 511;
        float s = bias[co];
        #pragma unroll
        for (int kc = 0; kc < 4; ++kc) s += part[((size_t)kc * 128 + b) * 512 + co];
        xo[t] = (bf16_t)(s > 0.f ? s : 0.f);
    }
}

__global__ __launch_bounds__(256, 2) void fc3_kernel(
    const bf16_t* __restrict__ x, const bf16_t* __restrict__ w,
    const float* __restrict__ bias, bf16_t* __restrict__ xo) {
    const int nb = blockIdx.x;
    const int wave = threadIdx.x >> 6, lane = threadIdx.x & 63;
    const int l15 = lane & 15, l4 = lane >> 4;

    f32x4 acc[2][4];
    #pragma unroll
    for (int m = 0; m < 2; ++m)
        #pragma unroll
        for (int n = 0; n < 4; ++n) acc[m][n] = f32x4{0.f, 0.f, 0.f, 0.f};

    uint32_t xb[2], wbf[4];
    #pragma unroll
    for (int m = 0; m < 2; ++m)
        xb[m] = (uint32_t)(16 * (wave * 2 + m) + l15) * 512u + l4 * 8u;
    #pragma unroll
    for (int n = 0; n < 4; ++n)
        wbf[n] = (uint32_t)(nb * 64 + n * 16 + l15) * 512u + l4 * 8u;

    #pragma unroll
    for (int s = 0; s < 16; ++s) {
        bf16x8 af[4];
        #pragma unroll
        for (int n = 0; n < 4; ++n) af[n] = load_frag<true>(w + wbf[n] + s * 32);
        #pragma unroll
        for (int m = 0; m < 2; ++m) {
            bf16x8 bfr = load_frag<true>(x + xb[m] + s * 32);
            #pragma unroll
            for (int n = 0; n < 4; ++n)
                acc[m][n] = mfma16(af[n], bfr, acc[m][n]);
        }
    }
    #pragma unroll
    for (int n = 0; n < 4; ++n) {
        int cf = nb * 64 + n * 16 + l4 * 4;
        f32x4 bv = *reinterpret_cast<const f32x4*>(bias + cf);
        #pragma unroll
        for (int m = 0; m < 2; ++m) {
            int brow = 16 * (wave * 2 + m) + l15;
            union { bf16x4 h; uint2 u; } st;
            #pragma unroll
            for (int r = 0; r < 4; ++r) {
                float v = acc[m][n][r] + bv[r];
                st.h[r] = (bf16_t)(v > 0.f ? v : 0.f);
            }
            *reinterpret_cast<uint2*>(xo + (size_t)brow * 512 + cf) = st.u;
        }
    }
}

__global__ void final_kernel(const bf16_t* __restrict__ x,
                             const float* __restrict__ eaw, const float* __restrict__ eab,
                             const float* __restrict__ evw, const float* __restrict__ evb,
                             float* __restrict__ out) {
    int b = blockIdx.x, lane = threadIdx.x;
    bf16x8 xv = *reinterpret_cast<const bf16x8*>(x + (size_t)b * 512 + lane * 8);
    float xs[8];
    #pragma unroll
    for (int i = 0; i < 8; ++i) xs[i] = (float)xv[i];
    float a[10];
    #pragma unroll
    for (int j = 0; j < 10; ++j) {
        const float* wr = (j < 9) ? (eaw + (size_t)j * 512) : evw;
        const f32x4* w4 = reinterpret_cast<const f32x4*>(wr + lane * 8);
        f32x4 w0 = w4[0], w1 = w4[1];
        float s = 0.f;
        #pragma unroll
        for (int i = 0; i < 4; ++i) s += xs[i] * w0[i];
        #pragma unroll
        for (int i = 0; i < 4; ++i) s += xs[4 + i] * w1[i];
        a[j] = s;
    }
    #pragma unroll
    for (int off = 1; off < 64; off <<= 1)
        #pragma unroll
        for (int j = 0; j < 10; ++j) a[j] += __shfl_xor(a[j], off);
    if (lane < 9) {
        float val  = a[9] + evb[0];
        float mean = 0.f;
        #pragma unroll
        for (int j = 0; j < 9; ++j) mean += a[j] + eab[j];
        mean *= (1.f / 9.f);
        out[b * 9 + lane] = a[lane] + eab[lane] + val - mean;
    }
}

// ---------------------------------------------------------------------------
extern "C" void kernel_launch(void* const* d_in, const int* in_sizes, int n_in,
                              void* d_out, int out_size, void* d_ws, size_t ws_size,
                              hipStream_t stream) {
    const float* state_m  = (const float*)d_in[0];
    const float* state_g  = (const float*)d_in[1];
    const float* state_v  = (const float*)d_in[2];
    const float* conv1_w  = (const float*)d_in[3];
    const float* conv1_b  = (const float*)d_in[4];
    const float* conv2_w  = (const float*)d_in[5];
    const float* conv2_b  = (const float*)d_in[6];
    const float* conv3_w  = (const float*)d_in[7];
    const float* conv3_b  = (const float*)d_in[8];
    const float* conv4_w  = (const float*)d_in[9];
    const float* conv4_b  = (const float*)d_in[10];
    const float* fc1_w    = (const float*)d_in[11];
    const float* fc1_b    = (const float*)d_in[12];
    const float* fc2_w    = (const float*)d_in[13];
    const float* fc2_b    = (const float*)d_in[14];
    const float* fc3_w    = (const float*)d_in[15];
    const float* fc3_b    = (const float*)d_in[16];
    const float* fc4_ea_w = (const float*)d_in[17];
    const float* fc4_ea_b = (const float*)d_in[18];
    const float* fc4_ev_w = (const float*)d_in[19];
    const float* fc4_ev_b = (const float*)d_in[20];

    char* ws = (char*)d_ws;
    // ---- weights & small buffers: [0, 14,418,176) -- never overwritten ----
    bf16_t* w1A    = (bf16_t*)(ws + 0);          //    262,144 conv1 frags
    bf16_t* w2A    = (bf16_t*)(ws + 262144);     //  4,194,304 conv2 frags
    bf16_t* w3A    = (bf16_t*)(ws + 4456448);    //    524,288 conv3 frags
    bf16_t* w4A    = (bf16_t*)(ws + 4980736);    //    524,288 conv4 frags
    bf16_t* w4p    = (bf16_t*)(ws + 5505024);    //    524,288 conv4c generic
    bf16_t* fc2wp  = (bf16_t*)(ws + 6029312);    //  6,553,600
    bf16_t* fc3wp  = (bf16_t*)(ws + 12582912);   //    524,288
    float*  scal   = (float*) (ws + 13107200);   //        256
    float*  part   = (float*) (ws + 13107456);   //  1,048,576
    bf16_t* x2fc   = (bf16_t*)(ws + 14156032);   //    131,072
    bf16_t* x3fc   = (bf16_t*)(ws + 14287104);   //    131,072
    // ---- activations (reuse only where producer strictly after consumer) --
    bf16_t* a0     = (bf16_t*)(ws + 14418176);   // 10,240,000 input NHWC
    bf16_t* x4a    = (bf16_t*)(ws + 14418176);   //  9,437,184 (a0 dead after conv1)
    bf16_t* x1     = (bf16_t*)(ws + 24658176);   // 39,002,112
    bf16_t* x4b    = (bf16_t*)(ws + 24658176);   //  4,734,976 (x1 dead after conv2)
    bf16_t* x4c    = (bf16_t*)(ws + 29393152);   //  1,638,400 (ditto; disjoint from x4b)
    bf16_t* x2     = (bf16_t*)(ws + 63660288);   // 23,658,496
    bf16_t* x3     = (bf16_t*)(ws + 87318784);   // 15,745,024 -> end 103,063,808
    (void)in_sizes; (void)n_in; (void)out_size; (void)ws_size;

    // weight packing + input layout conversion
    pack_wA<4, 32, 32> <<<dim3(64),   256, 0, stream>>>(conv1_w, w1A);
    pack_wA<32, 64, 32><<<dim3(1024), 256, 0, stream>>>(conv2_w, w2A);
    pack_wA<64, 64, 8> <<<dim3(128),  256, 0, stream>>>(conv3_w, w3A);
    pack_wA<64, 64, 8> <<<dim3(128),  256, 0, stream>>>(conv4_w, w4A);
    pack_w<64><<<dim3(16),   256, 0, stream>>>(conv4_w, w4p, 64, 64);
    pack_w<64><<<dim3(200),  256, 0, stream>>>(fc2_w, fc2wp, 512, 100);
    pack_w<1> <<<dim3(1024), 256, 0, stream>>>(fc3_w, fc3wp, 512, 512);
    pack_w<4> <<<dim3(1024), 256, 0, stream>>>(state_m, a0, 128, 10000);
    fc1_scalar<<<1, 64, 0, stream>>>(state_g, state_v, fc1_w, fc1_b, scal);

    // conv chain  conv_rr<CIN,COUT,W,K,OW,WMT,NSLOT,ADD_SCALAR>
    conv_rr<4, 32, 100, 32, 69, 3, 8, 0>
        <<<dim3(13, 1, 128), 256, 0, stream>>>(a0, w1A, conv1_b, x1, nullptr);
    conv_rr<32, 64, 69, 32, 38, 3, 12, 0>
        <<<dim3(4, 1, 128), 256, 0, stream>>>(x1, w2A, conv2_b, x2, nullptr);
    conv_rr<64, 64, 38, 8, 31, 2, 11, 1>
        <<<dim3(4, 1, 128), 256, 0, stream>>>(x2, w3A, conv3_b, x3, scal);
    conv_rr<64, 64, 31, 8, 24, 2, 13, 0>
        <<<dim3(3, 1, 128), 256, 0, stream>>>(x3, w4A, conv4_b, x4a, nullptr);
    conv_rr<64, 64, 24, 8, 17, 2, 17, 0>
        <<<dim3(2, 1, 128), 256, 0, stream>>>(x4a, w4A, conv4_b, x4b, nullptr);
    conv_mfma<64, 64, 17, 8, 10, 32, 1, 0, true>
        <<<dim3(2, 2, 128), 256, 0, stream>>>(x4b, w4p, conv4_b, x4c, nullptr);

    // FC head
    fc2_kernel<<<dim3(8, 4), 256, 0, stream>>>(x4c, fc2wp, part);
    fc2_reduce<<<dim3(256), 256, 0, stream>>>(part, fc2_b, x2fc);
    fc3_kernel<<<dim3(8), 256, 0, stream>>>(x2fc, fc3wp, fc3_b, x3fc);
    final_kernel<<<dim3(128), 64, 0, stream>>>(x3fc, fc4_ea_w, fc4_ea_b,
                                               fc4_ev_w, fc4_ev_b, (float*)d_out);
}

// Round 7
// 1213.441 us; speedup vs baseline: 1.2512x; 1.2512x over previous
//
#include <hip/hip_runtime.h>
#include <stdint.h>

// ---------------------------------------------------------------------------
// Dueling-DQN forward on MI355X. Round 7: DEPTH-templated conv_rr —
// conv2 keeps the 4-set/3-ahead pipeline (+setprio) and is re-tiled to
// WMT=2 / 768 blocks for 3 blocks/CU; small convs revert to the 1-deep
// round-5 structure that was fastest for them.
// ---------------------------------------------------------------------------

using bf16_t = __bf16;
using bf16x8 = __attribute__((ext_vector_type(8))) __bf16;
using bf16x4 = __attribute__((ext_vector_type(4))) __bf16;
using f32x4  = __attribute__((ext_vector_type(4))) float;
using f32x16 = __attribute__((ext_vector_type(16))) float;

__device__ __forceinline__ f32x4 mfma16(bf16x8 a, bf16x8 b, f32x4 c) {
    return __builtin_amdgcn_mfma_f32_16x16x32_bf16(a, b, c, 0, 0, 0);
}
__device__ __forceinline__ f32x16 mfma32(bf16x8 a, bf16x8 b, f32x16 c) {
    return __builtin_amdgcn_mfma_f32_32x32x16_bf16(a, b, c, 0, 0, 0);
}

template<bool A16>
__device__ __forceinline__ bf16x8 load_frag(const bf16_t* p) {
    if constexpr (A16) {
        return *reinterpret_cast<const bf16x8*>(p);
    } else {
        union { bf16x8 v; uint64_t u[2]; } r;
        r.u[0] = *reinterpret_cast<const uint64_t*>(p);
        r.u[1] = *reinterpret_cast<const uint64_t*>(p + 4);
        return r.v;
    }
}

// ---------------------------------------------------------------------------
// Generic pack: dst[cout][khw][cin] = (bf16)src[cout][cin][khw]
// ---------------------------------------------------------------------------
template<int CIN>
__global__ void pack_w(const float* __restrict__ src, bf16_t* __restrict__ dst,
                       int COUT, int KK) {
    int total = COUT * KK;
    for (int t = blockIdx.x * blockDim.x + threadIdx.x; t < total;
         t += gridDim.x * blockDim.x) {
        int cout = t / KK;
        int khw  = t - cout * KK;
        alignas(16) bf16_t tmp[CIN];
        #pragma unroll
        for (int c = 0; c < CIN; ++c)
            tmp[c] = (bf16_t)src[((size_t)cout * CIN + c) * KK + khw];
        bf16_t* d = dst + (size_t)t * CIN;
        if constexpr (CIN == 1) {
            d[0] = tmp[0];
        } else if constexpr (CIN == 4) {
            *reinterpret_cast<uint2*>(d) = *reinterpret_cast<const uint2*>(tmp);
        } else {
            #pragma unroll
            for (int c = 0; c < CIN; c += 8)
                *reinterpret_cast<uint4*>(d + c) =
                    *reinterpret_cast<const uint4*>(tmp + c);
        }
    }
}

// ---------------------------------------------------------------------------
// A-fragment pack for 32x32x16 MFMA conv: frag f = (kh*S + s)*NT + n holds
// couts n*32+(l&31); k = s*16 + (l>>5)*8 + e; k -> (kw = k/CIN, cin = k%CIN).
// ---------------------------------------------------------------------------
template<int CIN, int COUT, int K>
__global__ void pack_wA(const float* __restrict__ src, bf16_t* __restrict__ dst) {
    constexpr int S  = K * CIN / 16;
    constexpr int NT = COUT / 32;
    int t = blockIdx.x * 256 + threadIdx.x;
    int l  = t & 63;
    int f  = t >> 6;
    int n  = f % NT;
    int fs = f / NT;
    int s  = fs % S;
    int kh = fs / S;
    if (kh >= K) return;
    int cout = n * 32 + (l & 31);
    int k0   = s * 16 + (l >> 5) * 8;
    alignas(16) bf16_t tmp[8];
    #pragma unroll
    for (int e = 0; e < 8; ++e) {
        int k   = k0 + e;
        int kw  = k / CIN;
        int cin = k % CIN;
        tmp[e] = (bf16_t)src[(((size_t)cout * CIN + cin) * K + kh) * K + kw];
    }
    *reinterpret_cast<uint4*>(dst + (size_t)t * 8) =
        *reinterpret_cast<const uint4*>(tmp);
}

// scalar = relu(fc1(concat(g[0],v[0]))[30])
__global__ void fc1_scalar(const float* __restrict__ g, const float* __restrict__ v,
                           const float* __restrict__ w, const float* __restrict__ b,
                           float* __restrict__ outp) {
    if (threadIdx.x == 0 && blockIdx.x == 0) {
        float s = b[30] + g[0] * w[120] + g[1] * w[121] + v[0] * w[122] + v[1] * w[123];
        *outp = s > 0.f ? s : 0.f;
    }
}

// ---------------------------------------------------------------------------
// Rolling-row LDS implicit-GEMM conv, 32x32x16 MFMA. TR chunk-plane layout.
// DEPTH=1: round-5 1-deep pipeline. DEPTH=4: 4-set/3-ahead + setprio.
// ---------------------------------------------------------------------------
template<int CIN, int COUT, int W, int K, int OW, int WMT, int NSLOT,
         int ADD_SCALAR, int DEPTH>
__global__ __launch_bounds__(256, 2) void conv_rr(
    const bf16_t* __restrict__ in, const bf16_t* __restrict__ wA,
    const float* __restrict__ bias, bf16_t* __restrict__ out,
    const float* __restrict__ scal) {
    constexpr int  P     = OW * OW;
    constexpr int  PIXB  = CIN * 2;
    constexpr int  ROWB  = W * PIXB;
    constexpr bool TR    = (CIN >= 16);
    constexpr int  NCH   = TR ? PIXB / 16 : 1;
    constexpr int  SPP   = TR ? NCH / 2 : 1;
    constexpr int  PS    = TR ? (W + 1) * 16 : 0;
    constexpr int  SLOTB0 = TR ? NCH * PS : ROWB;
    constexpr int  PADB  = TR ? ((16 * OW - SLOTB0) % 128 + 128) % 128 : 0;
    constexpr int  SLOTB = SLOTB0 + PADB;
    constexpr int  LDSB  = NSLOT * SLOTB;
    constexpr int  S     = K * CIN / 16;
    constexpr int  NT    = COUT / 32;
    constexpr int  BPX   = WMT * 32 * 4;
    constexpr int  CH    = ROWB / 16;
    constexpr int  NLD   = (CH + 255) / 256;
    __shared__ __align__(16) char smem[LDSB];

    const int tid  = threadIdx.x;
    const int wave = tid >> 6, lane = tid & 63;
    const int l31  = lane & 31, h = lane >> 5;
    const int img  = blockIdx.z;
    const int p0   = blockIdx.x * BPX;

    const char* inb = (const char*)(in + (size_t)img * ((size_t)W * W * CIN));

    const int r0 = p0 / OW;
    int plast = p0 + BPX - 1; if (plast > P - 1) plast = P - 1;
    const int r1 = plast / OW;

    int woff[NLD];
    #pragma unroll
    for (int i = 0; i < NLD; ++i) {
        int c = i * 256 + tid;
        if (c < CH) woff[i] = TR ? (c % NCH) * PS + (c / NCH) * 16 : c * 16;
        else        woff[i] = 0;
    }

    int pix[WMT], ldsadr[WMT];
    #pragma unroll
    for (int m = 0; m < WMT; ++m) {
        int p  = p0 + (wave * WMT + m) * 32 + l31;
        pix[m] = p;
        int pc = p < P ? p : P - 1;
        int oh = pc / OW;
        int ow = pc - oh * OW;
        ldsadr[m] = (oh % NSLOT) * SLOTB +
                    (TR ? ow * 16 + h * PS : ow * PIXB + h * 16);
    }

    // prologue: stage rows r0..r1
    for (int r = r0; r <= r1; ++r) {
        const char* g = inb + (size_t)r * ROWB;
        int base = (r % NSLOT) * SLOTB;
        for (int c = tid; c < CH; c += 256) {
            bf16x8 v = *reinterpret_cast<const bf16x8*>(g + c * 16);
            int off = TR ? (c % NCH) * PS + (c / NCH) * 16 : c * 16;
            *reinterpret_cast<bf16x8*>(smem + base + off) = v;
        }
    }
    __syncthreads();

    f32x16 acc[WMT][NT] = {};

    int wsl = (r1 + 1) % NSLOT;
    const char* gpre = inb + (size_t)(r1 + 1) * ROWB;
    const bf16_t* wl = wA + lane * 8;

    for (int kh = 0; kh < K; ++kh) {
        bf16x8 stv[NLD];
        const bool pf = kh < K - 1;
        if (pf) {                                    // T14: issue early
            #pragma unroll
            for (int i = 0; i < NLD; ++i) {
                int c = i * 256 + tid;
                if (c < CH) stv[i] = *reinterpret_cast<const bf16x8*>(gpre + c * 16);
            }
        }
        const bf16_t* ap = wl + (size_t)kh * (S * NT * 512);

        if constexpr (DEPTH == 4) {
            // ---- 4-set, 3-ahead software pipeline over s ----
            bf16x8 bS0[WMT], bS1[WMT], bS2[WMT], bS3[WMT];
            bf16x8 aS0[NT],  aS1[NT],  aS2[NT],  aS3[NT];

#define LOADSET(BS, AS, SIDX)                                               \
            {                                                               \
                const int _s = (SIDX);                                      \
                _Pragma("unroll")                                           \
                for (int m = 0; m < WMT; ++m) {                             \
                    int a = TR ? ldsadr[m] + (_s % SPP) * (2 * PS) + (_s / SPP) * 16 \
                               : ldsadr[m] + _s * 32;                       \
                    BS[m] = *reinterpret_cast<const bf16x8*>(smem + a);     \
                }                                                           \
                _Pragma("unroll")                                           \
                for (int n = 0; n < NT; ++n)                                \
                    AS[n] = *reinterpret_cast<const bf16x8*>(ap + (_s * NT + n) * 512); \
            }
#define MFMASET(BS, AS)                                                     \
            {                                                               \
                __builtin_amdgcn_s_setprio(1);                              \
                _Pragma("unroll")                                           \
                for (int m = 0; m < WMT; ++m)                               \
                    _Pragma("unroll")                                       \
                    for (int n = 0; n < NT; ++n)                            \
                        acc[m][n] = mfma32(AS[n], BS[m], acc[m][n]);        \
                __builtin_amdgcn_s_setprio(0);                              \
            }

            LOADSET(bS0, aS0, 0)
            LOADSET(bS1, aS1, 1)
            LOADSET(bS2, aS2, 2)
            for (int sb = 0; sb + 8 <= S; sb += 4) {
                MFMASET(bS0, aS0)  LOADSET(bS3, aS3, sb + 3)
                MFMASET(bS1, aS1)  LOADSET(bS0, aS0, sb + 4)
                MFMASET(bS2, aS2)  LOADSET(bS1, aS1, sb + 5)
                MFMASET(bS3, aS3)  LOADSET(bS2, aS2, sb + 6)
            }
            MFMASET(bS0, aS0)  LOADSET(bS3, aS3, S - 1)
            MFMASET(bS1, aS1)
            MFMASET(bS2, aS2)
            MFMASET(bS3, aS3)
#undef LOADSET
#undef MFMASET
        } else {
            // ---- round-5 1-deep pipeline over s ----
            auto bread = [&](int m, int s) -> bf16x8 {
                int a = TR ? ldsadr[m] + (s % SPP) * (2 * PS) + (s / SPP) * 16
                           : ldsadr[m] + s * 32;
                return *reinterpret_cast<const bf16x8*>(smem + a);
            };
            bf16x8 bcur[WMT], acur[NT];
            #pragma unroll
            for (int m = 0; m < WMT; ++m) bcur[m] = bread(m, 0);
            #pragma unroll
            for (int n = 0; n < NT; ++n)
                acur[n] = *reinterpret_cast<const bf16x8*>(ap + n * 512);

            #pragma unroll 8
            for (int s = 0; s < S - 1; ++s) {
                bf16x8 bnx[WMT], anx[NT];
                #pragma unroll
                for (int m = 0; m < WMT; ++m) bnx[m] = bread(m, s + 1);
                #pragma unroll
                for (int n = 0; n < NT; ++n)
                    anx[n] = *reinterpret_cast<const bf16x8*>(ap + ((s + 1) * NT + n) * 512);
                #pragma unroll
                for (int m = 0; m < WMT; ++m)
                    #pragma unroll
                    for (int n = 0; n < NT; ++n)
                        acc[m][n] = mfma32(acur[n], bcur[m], acc[m][n]);
                #pragma unroll
                for (int m = 0; m < WMT; ++m) bcur[m] = bnx[m];
                #pragma unroll
                for (int n = 0; n < NT; ++n) acur[n] = anx[n];
            }
            #pragma unroll
            for (int m = 0; m < WMT; ++m)
                #pragma unroll
                for (int n = 0; n < NT; ++n)
                    acc[m][n] = mfma32(acur[n], bcur[m], acc[m][n]);
        }

        if (pf) {                                    // write-late
            int wb0 = wsl * SLOTB;
            #pragma unroll
            for (int i = 0; i < NLD; ++i) {
                int c = i * 256 + tid;
                if (c < CH)
                    *reinterpret_cast<bf16x8*>(smem + wb0 + woff[i]) = stv[i];
            }
            gpre += ROWB;
            wsl = (wsl + 1 == NSLOT) ? 0 : wsl + 1;
        }
        __syncthreads();
        #pragma unroll
        for (int m = 0; m < WMT; ++m) {
            int a2 = ldsadr[m] + SLOTB;
            ldsadr[m] = a2 >= LDSB ? a2 - LDSB : a2;
        }
    }

    float sc = 0.f;
    if constexpr (ADD_SCALAR) sc = *scal;
    bf16_t* outb = out + (size_t)img * ((size_t)P * COUT);
    #pragma unroll
    for (int m = 0; m < WMT; ++m) {
        if (pix[m] < P) {
            #pragma unroll
            for (int n = 0; n < NT; ++n) {
                #pragma unroll
                for (int rg = 0; rg < 4; ++rg) {
                    int cb = n * 32 + rg * 8 + h * 4;
                    f32x4 bv = *reinterpret_cast<const f32x4*>(bias + cb);
                    union { bf16x4 v; uint2 u; } o;
                    #pragma unroll
                    for (int j = 0; j < 4; ++j) {
                        float x = acc[m][n][rg * 4 + j] + bv[j];
                        x = x > 0.f ? x : 0.f;
                        x += sc;
                        o.v[j] = (bf16_t)x;
                    }
                    *reinterpret_cast<uint2*>(outb + (size_t)pix[m] * COUT + cb) = o.u;
                }
            }
        }
    }
}

// ---------------------------------------------------------------------------
// Generic implicit-GEMM conv (16x16x32) via global loads — used for conv4c.
// ---------------------------------------------------------------------------
template<int CIN, int COUT, int W, int K, int OW, int NBLK, int WMT,
         int ADD_SCALAR, bool A16>
__global__ __launch_bounds__(256, 2) void conv_mfma(
    const bf16_t* __restrict__ in, const bf16_t* __restrict__ wp,
    const float* __restrict__ bias, bf16_t* __restrict__ out,
    const float* __restrict__ scal) {
    constexpr int P    = OW * OW;
    constexpr int KCIN = K * CIN;
    constexpr int KTOT = K * KCIN;
    constexpr int RS   = KCIN / 32;
    constexpr int NT   = NBLK / 16;
    constexpr int BMT  = WMT * 4;

    const int b     = blockIdx.z;
    const int cout0 = blockIdx.y * NBLK;
    const int wave  = threadIdx.x >> 6;
    const int lane  = threadIdx.x & 63;
    const int l15   = lane & 15;
    const int l4    = lane >> 4;
    const int mt0   = blockIdx.x * BMT + wave * WMT;

    const bf16_t* inb = in + (size_t)b * (W * W * CIN);

    int      pix[WMT];
    uint32_t pb[WMT];
    #pragma unroll
    for (int m = 0; m < WMT; ++m) {
        int p  = (mt0 + m) * 16 + l15;
        pix[m] = p;
        int pc = p < P ? p : P - 1;
        int oh = pc / OW;
        int ow = pc - oh * OW;
        pb[m]  = (uint32_t)(oh * W + ow) * CIN;
    }
    uint32_t wb[NT];
    #pragma unroll
    for (int n = 0; n < NT; ++n)
        wb[n] = (uint32_t)(cout0 + n * 16 + l15) * KTOT + (uint32_t)l4 * 8u;

    f32x4 acc[WMT][NT];
    #pragma unroll
    for (int m = 0; m < WMT; ++m)
        #pragma unroll
        for (int n = 0; n < NT; ++n)
            acc[m][n] = f32x4{0.f, 0.f, 0.f, 0.f};

    uint32_t bofs = (uint32_t)l4 * 8u;
    for (int kh = 0; kh < K; ++kh) {
        #pragma unroll
        for (int s = 0; s < RS; ++s) {
            bf16x8 af[NT];
            #pragma unroll
            for (int n = 0; n < NT; ++n)
                af[n] = load_frag<true>(wp + wb[n] + kh * KCIN + s * 32);
            #pragma unroll
            for (int m = 0; m < WMT; ++m) {
                bf16x8 bfr = load_frag<A16>(inb + pb[m] + bofs + s * 32);
                #pragma unroll
                for (int n = 0; n < NT; ++n)
                    acc[m][n] = mfma16(af[n], bfr, acc[m][n]);
            }
        }
        bofs += (uint32_t)(W * CIN);
    }

    float sc = 0.f;
    if constexpr (ADD_SCALAR) sc = *scal;
    bf16_t* outb = out + (size_t)b * P * COUT;
    #pragma unroll
    for (int n = 0; n < NT; ++n) {
        const int cb = cout0 + n * 16 + l4 * 4;
        f32x4 bv = *reinterpret_cast<const f32x4*>(bias + cb);
        #pragma unroll
        for (int m = 0; m < WMT; ++m) {
            if (pix[m] < P) {
                f32x4 v = acc[m][n];
                union { bf16x4 h; uint2 u; } st;
                #pragma unroll
                for (int r = 0; r < 4; ++r) {
                    float x = v[r] + bv[r];
                    x = x > 0.f ? x : 0.f;
                    x += sc;
                    st.h[r] = (bf16_t)x;
                }
                *reinterpret_cast<uint2*>(outb + (size_t)pix[m] * COUT + cb) = st.u;
            }
        }
    }
}

// ---------------------------------------------------------------------------
// fc2: [128,6400]x[512,6400]^T, K-split x4 into f32 partials.
// ---------------------------------------------------------------------------
__global__ __launch_bounds__(256, 2) void fc2_kernel(
    const bf16_t* __restrict__ x, const bf16_t* __restrict__ w,
    float* __restrict__ part) {
    const int nb = blockIdx.x, kc = blockIdx.y;
    const int wave = threadIdx.x >> 6, lane = threadIdx.x & 63;
    const int l15 = lane & 15, l4 = lane >> 4;
    const int wm = wave & 1, wn = wave >> 1;

    f32x4 acc[4][2];
    #pragma unroll
    for (int m = 0; m < 4; ++m)
        #pragma unroll
        for (int n = 0; n < 2; ++n) acc[m][n] = f32x4{0.f, 0.f, 0.f, 0.f};

    uint32_t xb[4], wbf[2];
    #pragma unroll
    for (int m = 0; m < 4; ++m)
        xb[m] = (uint32_t)(16 * (wm * 4 + m) + l15) * 6400u + kc * 1600u + l4 * 8u;
    #pragma unroll
    for (int n = 0; n < 2; ++n)
        wbf[n] = (uint32_t)(nb * 64 + wn * 32 + n * 16 + l15) * 6400u + kc * 1600u + l4 * 8u;

    for (int s = 0; s < 50; ++s) {
        bf16x8 af[2];
        #pragma unroll
        for (int n = 0; n < 2; ++n)
            af[n] = load_frag<true>(w + wbf[n] + s * 32);
        #pragma unroll
        for (int m = 0; m < 4; ++m) {
            bf16x8 bfr = load_frag<true>(x + xb[m] + s * 32);
            #pragma unroll
            for (int n = 0; n < 2; ++n)
                acc[m][n] = mfma16(af[n], bfr, acc[m][n]);
        }
    }
    #pragma unroll
    for (int m = 0; m < 4; ++m) {
        int bcol = 16 * (wm * 4 + m) + l15;
        #pragma unroll
        for (int n = 0; n < 2; ++n) {
            int cf = nb * 64 + wn * 32 + n * 16 + l4 * 4;
            *reinterpret_cast<f32x4*>(part + ((size_t)kc * 128 + bcol) * 512 + cf) =
                acc[m][n];
        }
    }
}

__global__ void fc2_reduce(const float* __restrict__ part,
                           const float* __restrict__ bias,
                           bf16_t* __restrict__ xo) {
    int t = blockIdx.x * 256 + threadIdx.x;
    if (t < 128 * 512) {
        int b = t >> 9, co = t & 511;
        float s = bias[co];
        #pragma unroll
        for (int kc = 0; kc < 4; ++kc) s += part[((size_t)kc * 128 + b) * 512 + co];
        xo[t] = (bf16_t)(s > 0.f ? s : 0.f);
    }
}

__global__ __launch_bounds__(256, 2) void fc3_kernel(
    const bf16_t* __restrict__ x, const bf16_t* __restrict__ w,
    const float* __restrict__ bias, bf16_t* __restrict__ xo) {
    const int nb = blockIdx.x;
    const int wave = threadIdx.x >> 6, lane = threadIdx.x & 63;
    const int l15 = lane & 15, l4 = lane >> 4;

    f32x4 acc[2][4];
    #pragma unroll
    for (int m = 0; m < 2; ++m)
        #pragma unroll
        for (int n = 0; n < 4; ++n) acc[m][n] = f32x4{0.f, 0.f, 0.f, 0.f};

    uint32_t xb[2], wbf[4];
    #pragma unroll
    for (int m = 0; m < 2; ++m)
        xb[m] = (uint32_t)(16 * (wave * 2 + m) + l15) * 512u + l4 * 8u;
    #pragma unroll
    for (int n = 0; n < 4; ++n)
        wbf[n] = (uint32_t)(nb * 64 + n * 16 + l15) * 512u + l4 * 8u;

    #pragma unroll
    for (int s = 0; s < 16; ++s) {
        bf16x8 af[4];
        #pragma unroll
        for (int n = 0; n < 4; ++n) af[n] = load_frag<true>(w + wbf[n] + s * 32);
        #pragma unroll
        for (int m = 0; m < 2; ++m) {
            bf16x8 bfr = load_frag<true>(x + xb[m] + s * 32);
            #pragma unroll
            for (int n = 0; n < 4; ++n)
                acc[m][n] = mfma16(af[n], bfr, acc[m][n]);
        }
    }
    #pragma unroll
    for (int n = 0; n < 4; ++n) {
        int cf = nb * 64 + n * 16 + l4 * 4;
        f32x4 bv = *reinterpret_cast<const f32x4*>(bias + cf);
        #pragma unroll
        for (int m = 0; m < 2; ++m) {
            int brow = 16 * (wave * 2 + m) + l15;
            union { bf16x4 h; uint2 u; } st;
            #pragma unroll
            for (int r = 0; r < 4; ++r) {
                float v = acc[m][n][r] + bv[r];
                st.h[r] = (bf16_t)(v > 0.f ? v : 0.f);
            }
            *reinterpret_cast<uint2*>(xo + (size_t)brow * 512 + cf) = st.u;
        }
    }
}

__global__ void final_kernel(const bf16_t* __restrict__ x,
                             const float* __restrict__ eaw, const float* __restrict__ eab,
                             const float* __restrict__ evw, const float* __restrict__ evb,
                             float* __restrict__ out) {
    int b = blockIdx.x, lane = threadIdx.x;
    bf16x8 xv = *reinterpret_cast<const bf16x8*>(x + (size_t)b * 512 + lane * 8);
    float xs[8];
    #pragma unroll
    for (int i = 0; i < 8; ++i) xs[i] = (float)xv[i];
    float a[10];
    #pragma unroll
    for (int j = 0; j < 10; ++j) {
        const float* wr = (j < 9) ? (eaw + (size_t)j * 512) : evw;
        const f32x4* w4 = reinterpret_cast<const f32x4*>(wr + lane * 8);
        f32x4 w0 = w4[0], w1 = w4[1];
        float s = 0.f;
        #pragma unroll
        for (int i = 0; i < 4; ++i) s += xs[i] * w0[i];
        #pragma unroll
        for (int i = 0; i < 4; ++i) s += xs[4 + i] * w1[i];
        a[j] = s;
    }
    #pragma unroll
    for (int off = 1; off < 64; off <<= 1)
        #pragma unroll
        for (int j = 0; j < 10; ++j) a[j] += __shfl_xor(a[j], off);
    if (lane < 9) {
        float val  = a[9] + evb[0];
        float mean = 0.f;
        #pragma unroll
        for (int j = 0; j < 9; ++j) mean += a[j] + eab[j];
        mean *= (1.f / 9.f);
        out[b * 9 + lane] = a[lane] + eab[lane] + val - mean;
    }
}

// ---------------------------------------------------------------------------
extern "C" void kernel_launch(void* const* d_in, const int* in_sizes, int n_in,
                              void* d_out, int out_size, void* d_ws, size_t ws_size,
                              hipStream_t stream) {
    const float* state_m  = (const float*)d_in[0];
    const float* state_g  = (const float*)d_in[1];
    const float* state_v  = (const float*)d_in[2];
    const float* conv1_w  = (const float*)d_in[3];
    const float* conv1_b  = (const float*)d_in[4];
    const float* conv2_w  = (const float*)d_in[5];
    const float* conv2_b  = (const float*)d_in[6];
    const float* conv3_w  = (const float*)d_in[7];
    const float* conv3_b  = (const float*)d_in[8];
    const float* conv4_w  = (const float*)d_in[9];
    const float* conv4_b  = (const float*)d_in[10];
    const float* fc1_w    = (const float*)d_in[11];
    const float* fc1_b    = (const float*)d_in[12];
    const float* fc2_w    = (const float*)d_in[13];
    const float* fc2_b    = (const float*)d_in[14];
    const float* fc3_w    = (const float*)d_in[15];
    const float* fc3_b    = (const float*)d_in[16];
    const float* fc4_ea_w = (const float*)d_in[17];
    const float* fc4_ea_b = (const float*)d_in[18];
    const float* fc4_ev_w = (const float*)d_in[19];
    const float* fc4_ev_b = (const float*)d_in[20];

    char* ws = (char*)d_ws;
    // ---- weights & small buffers: [0, 14,418,176) -- never overwritten ----
    bf16_t* w1A    = (bf16_t*)(ws + 0);          //    262,144 conv1 frags
    bf16_t* w2A    = (bf16_t*)(ws + 262144);     //  4,194,304 conv2 frags
    bf16_t* w3A    = (bf16_t*)(ws + 4456448);    //    524,288 conv3 frags
    bf16_t* w4A    = (bf16_t*)(ws + 4980736);    //    524,288 conv4 frags
    bf16_t* w4p    = (bf16_t*)(ws + 5505024);    //    524,288 conv4c generic
    bf16_t* fc2wp  = (bf16_t*)(ws + 6029312);    //  6,553,600
    bf16_t* fc3wp  = (bf16_t*)(ws + 12582912);   //    524,288
    float*  scal   = (float*) (ws + 13107200);   //        256
    float*  part   = (float*) (ws + 13107456);   //  1,048,576
    bf16_t* x2fc   = (bf16_t*)(ws + 14156032);   //    131,072
    bf16_t* x3fc   = (bf16_t*)(ws + 14287104);   //    131,072
    // ---- activations (reuse only where producer strictly after consumer) --
    bf16_t* a0     = (bf16_t*)(ws + 14418176);   // 10,240,000 input NHWC
    bf16_t* x4a    = (bf16_t*)(ws + 14418176);   //  9,437,184 (a0 dead after conv1)
    bf16_t* x1     = (bf16_t*)(ws + 24658176);   // 39,002,112
    bf16_t* x4b    = (bf16_t*)(ws + 24658176);   //  4,734,976 (x1 dead after conv2)
    bf16_t* x4c    = (bf16_t*)(ws + 29393152);   //  1,638,400 (ditto; disjoint from x4b)
    bf16_t* x2     = (bf16_t*)(ws + 63660288);   // 23,658,496
    bf16_t* x3     = (bf16_t*)(ws + 87318784);   // 15,745,024 -> end 103,063,808
    (void)in_sizes; (void)n_in; (void)out_size; (void)ws_size;

    // weight packing + input layout conversion
    pack_wA<4, 32, 32> <<<dim3(64),   256, 0, stream>>>(conv1_w, w1A);
    pack_wA<32, 64, 32><<<dim3(1024), 256, 0, stream>>>(conv2_w, w2A);
    pack_wA<64, 64, 8> <<<dim3(128),  256, 0, stream>>>(conv3_w, w3A);
    pack_wA<64, 64, 8> <<<dim3(128),  256, 0, stream>>>(conv4_w, w4A);
    pack_w<64><<<dim3(16),   256, 0, stream>>>(conv4_w, w4p, 64, 64);
    pack_w<64><<<dim3(200),  256, 0, stream>>>(fc2_w, fc2wp, 512, 100);
    pack_w<1> <<<dim3(1024), 256, 0, stream>>>(fc3_w, fc3wp, 512, 512);
    pack_w<4> <<<dim3(1024), 256, 0, stream>>>(state_m, a0, 128, 10000);
    fc1_scalar<<<1, 64, 0, stream>>>(state_g, state_v, fc1_w, fc1_b, scal);

    // conv chain  conv_rr<CIN,COUT,W,K,OW,WMT,NSLOT,ADD_SCALAR,DEPTH>
    conv_rr<4, 32, 100, 32, 69, 3, 8, 0, 1>
        <<<dim3(13, 1, 128), 256, 0, stream>>>(a0, w1A, conv1_b, x1, nullptr);
    conv_rr<32, 64, 69, 32, 38, 2, 9, 0, 4>       // 768 blocks = 3/CU
        <<<dim3(6, 1, 128), 256, 0, stream>>>(x1, w2A, conv2_b, x2, nullptr);
    conv_rr<64, 64, 38, 8, 31, 2, 11, 1, 1>
        <<<dim3(4, 1, 128), 256, 0, stream>>>(x2, w3A, conv3_b, x3, scal);
    conv_rr<64, 64, 31, 8, 24, 2, 13, 0, 1>
        <<<dim3(3, 1, 128), 256, 0, stream>>>(x3, w4A, conv4_b, x4a, nullptr);
    conv_rr<64, 64, 24, 8, 17, 2, 17, 0, 1>
        <<<dim3(2, 1, 128), 256, 0, stream>>>(x4a, w4A, conv4_b, x4b, nullptr);
    conv_mfma<64, 64, 17, 8, 10, 32, 1, 0, true>
        <<<dim3(2, 2, 128), 256, 0, stream>>>(x4b, w4p, conv4_b, x4c, nullptr);

    // FC head
    fc2_kernel<<<dim3(8, 4), 256, 0, stream>>>(x4c, fc2wp, part);
    fc2_reduce<<<dim3(256), 256, 0, stream>>>(part, fc2_b, x2fc);
    fc3_kernel<<<dim3(8), 256, 0, stream>>>(x2fc, fc3wp, fc3_b, x3fc);
    final_kernel<<<dim3(128), 64, 0, stream>>>(x3fc, fc4_ea_w, fc4_ea_b,
                                               fc4_ev_w, fc4_ev_b, (float*)d_out);
}

// Round 8
// 1177.053 us; speedup vs baseline: 1.2898x; 1.0309x over previous
//
#include <hip/hip_runtime.h>
#include <stdint.h>

// ---------------------------------------------------------------------------
// Dueling-DQN forward on MI355X. Round 8: defer the per-kh row-prefetch issue
// until after the leading A/B fragment loads are in the vmcnt queue (in-order
// vmcnt retire means an early HBM prefetch stalls the first MFMA of every kh
// phase). DEPTH4: peel first group, issue stv after it. DEPTH1: issue at s==2.
// ---------------------------------------------------------------------------

using bf16_t = __bf16;
using bf16x8 = __attribute__((ext_vector_type(8))) __bf16;
using bf16x4 = __attribute__((ext_vector_type(4))) __bf16;
using f32x4  = __attribute__((ext_vector_type(4))) float;
using f32x16 = __attribute__((ext_vector_type(16))) float;

__device__ __forceinline__ f32x4 mfma16(bf16x8 a, bf16x8 b, f32x4 c) {
    return __builtin_amdgcn_mfma_f32_16x16x32_bf16(a, b, c, 0, 0, 0);
}
__device__ __forceinline__ f32x16 mfma32(bf16x8 a, bf16x8 b, f32x16 c) {
    return __builtin_amdgcn_mfma_f32_32x32x16_bf16(a, b, c, 0, 0, 0);
}

template<bool A16>
__device__ __forceinline__ bf16x8 load_frag(const bf16_t* p) {
    if constexpr (A16) {
        return *reinterpret_cast<const bf16x8*>(p);
    } else {
        union { bf16x8 v; uint64_t u[2]; } r;
        r.u[0] = *reinterpret_cast<const uint64_t*>(p);
        r.u[1] = *reinterpret_cast<const uint64_t*>(p + 4);
        return r.v;
    }
}

// ---------------------------------------------------------------------------
// Generic pack: dst[cout][khw][cin] = (bf16)src[cout][cin][khw]
// ---------------------------------------------------------------------------
template<int CIN>
__global__ void pack_w(const float* __restrict__ src, bf16_t* __restrict__ dst,
                       int COUT, int KK) {
    int total = COUT * KK;
    for (int t = blockIdx.x * blockDim.x + threadIdx.x; t < total;
         t += gridDim.x * blockDim.x) {
        int cout = t / KK;
        int khw  = t - cout * KK;
        alignas(16) bf16_t tmp[CIN];
        #pragma unroll
        for (int c = 0; c < CIN; ++c)
            tmp[c] = (bf16_t)src[((size_t)cout * CIN + c) * KK + khw];
        bf16_t* d = dst + (size_t)t * CIN;
        if constexpr (CIN == 1) {
            d[0] = tmp[0];
        } else if constexpr (CIN == 4) {
            *reinterpret_cast<uint2*>(d) = *reinterpret_cast<const uint2*>(tmp);
        } else {
            #pragma unroll
            for (int c = 0; c < CIN; c += 8)
                *reinterpret_cast<uint4*>(d + c) =
                    *reinterpret_cast<const uint4*>(tmp + c);
        }
    }
}

// ---------------------------------------------------------------------------
// A-fragment pack for 32x32x16 MFMA conv: frag f = (kh*S + s)*NT + n holds
// couts n*32+(l&31); k = s*16 + (l>>5)*8 + e; k -> (kw = k/CIN, cin = k%CIN).
// ---------------------------------------------------------------------------
template<int CIN, int COUT, int K>
__global__ void pack_wA(const float* __restrict__ src, bf16_t* __restrict__ dst) {
    constexpr int S  = K * CIN / 16;
    constexpr int NT = COUT / 32;
    int t = blockIdx.x * 256 + threadIdx.x;
    int l  = t & 63;
    int f  = t >> 6;
    int n  = f % NT;
    int fs = f / NT;
    int s  = fs % S;
    int kh = fs / S;
    if (kh >= K) return;
    int cout = n * 32 + (l & 31);
    int k0   = s * 16 + (l >> 5) * 8;
    alignas(16) bf16_t tmp[8];
    #pragma unroll
    for (int e = 0; e < 8; ++e) {
        int k   = k0 + e;
        int kw  = k / CIN;
        int cin = k % CIN;
        tmp[e] = (bf16_t)src[(((size_t)cout * CIN + cin) * K + kh) * K + kw];
    }
    *reinterpret_cast<uint4*>(dst + (size_t)t * 8) =
        *reinterpret_cast<const uint4*>(tmp);
}

// scalar = relu(fc1(concat(g[0],v[0]))[30])
__global__ void fc1_scalar(const float* __restrict__ g, const float* __restrict__ v,
                           const float* __restrict__ w, const float* __restrict__ b,
                           float* __restrict__ outp) {
    if (threadIdx.x == 0 && blockIdx.x == 0) {
        float s = b[30] + g[0] * w[120] + g[1] * w[121] + v[0] * w[122] + v[1] * w[123];
        *outp = s > 0.f ? s : 0.f;
    }
}

// ---------------------------------------------------------------------------
// Rolling-row LDS implicit-GEMM conv, 32x32x16 MFMA. TR chunk-plane layout.
// DEPTH=1: 1-deep pipeline, stv issued at s==2. DEPTH=4: 4-set/3-ahead with
// peeled first group, stv issued after it; setprio around MFMA clusters.
// ---------------------------------------------------------------------------
template<int CIN, int COUT, int W, int K, int OW, int WMT, int NSLOT,
         int ADD_SCALAR, int DEPTH>
__global__ __launch_bounds__(256, 2) void conv_rr(
    const bf16_t* __restrict__ in, const bf16_t* __restrict__ wA,
    const float* __restrict__ bias, bf16_t* __restrict__ out,
    const float* __restrict__ scal) {
    constexpr int  P     = OW * OW;
    constexpr int  PIXB  = CIN * 2;
    constexpr int  ROWB  = W * PIXB;
    constexpr bool TR    = (CIN >= 16);
    constexpr int  NCH   = TR ? PIXB / 16 : 1;
    constexpr int  SPP   = TR ? NCH / 2 : 1;
    constexpr int  PS    = TR ? (W + 1) * 16 : 0;
    constexpr int  SLOTB0 = TR ? NCH * PS : ROWB;
    constexpr int  PADB  = TR ? ((16 * OW - SLOTB0) % 128 + 128) % 128 : 0;
    constexpr int  SLOTB = SLOTB0 + PADB;
    constexpr int  LDSB  = NSLOT * SLOTB;
    constexpr int  S     = K * CIN / 16;
    constexpr int  NT    = COUT / 32;
    constexpr int  BPX   = WMT * 32 * 4;
    constexpr int  CH    = ROWB / 16;
    constexpr int  NLD   = (CH + 255) / 256;
    __shared__ __align__(16) char smem[LDSB];

    const int tid  = threadIdx.x;
    const int wave = tid >> 6, lane = tid & 63;
    const int l31  = lane & 31, h = lane >> 5;
    const int img  = blockIdx.z;
    const int p0   = blockIdx.x * BPX;

    const char* inb = (const char*)(in + (size_t)img * ((size_t)W * W * CIN));

    const int r0 = p0 / OW;
    int plast = p0 + BPX - 1; if (plast > P - 1) plast = P - 1;
    const int r1 = plast / OW;

    int woff[NLD];
    #pragma unroll
    for (int i = 0; i < NLD; ++i) {
        int c = i * 256 + tid;
        if (c < CH) woff[i] = TR ? (c % NCH) * PS + (c / NCH) * 16 : c * 16;
        else        woff[i] = 0;
    }

    int pix[WMT], ldsadr[WMT];
    #pragma unroll
    for (int m = 0; m < WMT; ++m) {
        int p  = p0 + (wave * WMT + m) * 32 + l31;
        pix[m] = p;
        int pc = p < P ? p : P - 1;
        int oh = pc / OW;
        int ow = pc - oh * OW;
        ldsadr[m] = (oh % NSLOT) * SLOTB +
                    (TR ? ow * 16 + h * PS : ow * PIXB + h * 16);
    }

    // prologue: stage rows r0..r1
    for (int r = r0; r <= r1; ++r) {
        const char* g = inb + (size_t)r * ROWB;
        int base = (r % NSLOT) * SLOTB;
        for (int c = tid; c < CH; c += 256) {
            bf16x8 v = *reinterpret_cast<const bf16x8*>(g + c * 16);
            int off = TR ? (c % NCH) * PS + (c / NCH) * 16 : c * 16;
            *reinterpret_cast<bf16x8*>(smem + base + off) = v;
        }
    }
    __syncthreads();

    f32x16 acc[WMT][NT] = {};

    int wsl = (r1 + 1) % NSLOT;
    const char* gpre = inb + (size_t)(r1 + 1) * ROWB;
    const bf16_t* wl = wA + lane * 8;

    for (int kh = 0; kh < K; ++kh) {
        bf16x8 stv[NLD];
        const bool pf = kh < K - 1;
        const bf16_t* ap = wl + (size_t)kh * (S * NT * 512);

#define STVISSUE                                                            \
        if (pf) {                                                           \
            _Pragma("unroll")                                               \
            for (int i = 0; i < NLD; ++i) {                                 \
                int c = i * 256 + tid;                                      \
                if (c < CH) stv[i] = *reinterpret_cast<const bf16x8*>(gpre + c * 16); \
            }                                                               \
        }

        if constexpr (DEPTH == 4) {
            // ---- 4-set, 3-ahead software pipeline over s ----
            bf16x8 bS0[WMT], bS1[WMT], bS2[WMT], bS3[WMT];
            bf16x8 aS0[NT],  aS1[NT],  aS2[NT],  aS3[NT];

#define LOADSET(BS, AS, SIDX)                                               \
            {                                                               \
                const int _s = (SIDX);                                      \
                _Pragma("unroll")                                           \
                for (int m = 0; m < WMT; ++m) {                             \
                    int a = TR ? ldsadr[m] + (_s % SPP) * (2 * PS) + (_s / SPP) * 16 \
                               : ldsadr[m] + _s * 32;                       \
                    BS[m] = *reinterpret_cast<const bf16x8*>(smem + a);     \
                }                                                           \
                _Pragma("unroll")                                           \
                for (int n = 0; n < NT; ++n)                                \
                    AS[n] = *reinterpret_cast<const bf16x8*>(ap + (_s * NT + n) * 512); \
            }
#define MFMASET(BS, AS)                                                     \
            {                                                               \
                __builtin_amdgcn_s_setprio(1);                              \
                _Pragma("unroll")                                           \
                for (int m = 0; m < WMT; ++m)                               \
                    _Pragma("unroll")                                       \
                    for (int n = 0; n < NT; ++n)                            \
                        acc[m][n] = mfma32(AS[n], BS[m], acc[m][n]);        \
                __builtin_amdgcn_s_setprio(0);                              \
            }

            LOADSET(bS0, aS0, 0)
            LOADSET(bS1, aS1, 1)
            LOADSET(bS2, aS2, 2)
            // peeled first group: get 7 LOADSETs into the vmcnt queue
            MFMASET(bS0, aS0)  LOADSET(bS3, aS3, 3)
            MFMASET(bS1, aS1)  LOADSET(bS0, aS0, 4)
            MFMASET(bS2, aS2)  LOADSET(bS1, aS1, 5)
            MFMASET(bS3, aS3)  LOADSET(bS2, aS2, 6)
            // row prefetch issued AFTER the leading fragment loads (vmcnt is
            // in-order: issuing it first would stall set-0's MFMA on HBM)
            STVISSUE
            for (int sb = 4; sb + 8 <= S; sb += 4) {
                MFMASET(bS0, aS0)  LOADSET(bS3, aS3, sb + 3)
                MFMASET(bS1, aS1)  LOADSET(bS0, aS0, sb + 4)
                MFMASET(bS2, aS2)  LOADSET(bS1, aS1, sb + 5)
                MFMASET(bS3, aS3)  LOADSET(bS2, aS2, sb + 6)
            }
            MFMASET(bS0, aS0)  LOADSET(bS3, aS3, S - 1)
            MFMASET(bS1, aS1)
            MFMASET(bS2, aS2)
            MFMASET(bS3, aS3)
#undef LOADSET
#undef MFMASET
        } else {
            // ---- 1-deep pipeline over s, stv issued at s==2 ----
            auto bread = [&](int m, int s) -> bf16x8 {
                int a = TR ? ldsadr[m] + (s % SPP) * (2 * PS) + (s / SPP) * 16
                           : ldsadr[m] + s * 32;
                return *reinterpret_cast<const bf16x8*>(smem + a);
            };
            bf16x8 bcur[WMT], acur[NT];
            #pragma unroll
            for (int m = 0; m < WMT; ++m) bcur[m] = bread(m, 0);
            #pragma unroll
            for (int n = 0; n < NT; ++n)
                acur[n] = *reinterpret_cast<const bf16x8*>(ap + n * 512);

            #pragma unroll
            for (int s = 0; s < S - 1; ++s) {
                bf16x8 bnx[WMT], anx[NT];
                #pragma unroll
                for (int m = 0; m < WMT; ++m) bnx[m] = bread(m, s + 1);
                #pragma unroll
                for (int n = 0; n < NT; ++n)
                    anx[n] = *reinterpret_cast<const bf16x8*>(ap + ((s + 1) * NT + n) * 512);
                if (s == 2) { STVISSUE }
                #pragma unroll
                for (int m = 0; m < WMT; ++m)
                    #pragma unroll
                    for (int n = 0; n < NT; ++n)
                        acc[m][n] = mfma32(acur[n], bcur[m], acc[m][n]);
                #pragma unroll
                for (int m = 0; m < WMT; ++m) bcur[m] = bnx[m];
                #pragma unroll
                for (int n = 0; n < NT; ++n) acur[n] = anx[n];
            }
            #pragma unroll
            for (int m = 0; m < WMT; ++m)
                #pragma unroll
                for (int n = 0; n < NT; ++n)
                    acc[m][n] = mfma32(acur[n], bcur[m], acc[m][n]);
        }
#undef STVISSUE

        if (pf) {                                    // write-late
            int wb0 = wsl * SLOTB;
            #pragma unroll
            for (int i = 0; i < NLD; ++i) {
                int c = i * 256 + tid;
                if (c < CH)
                    *reinterpret_cast<bf16x8*>(smem + wb0 + woff[i]) = stv[i];
            }
            gpre += ROWB;
            wsl = (wsl + 1 == NSLOT) ? 0 : wsl + 1;
        }
        __syncthreads();
        #pragma unroll
        for (int m = 0; m < WMT; ++m) {
            int a2 = ldsadr[m] + SLOTB;
            ldsadr[m] = a2 >= LDSB ? a2 - LDSB : a2;
        }
    }

    float sc = 0.f;
    if constexpr (ADD_SCALAR) sc = *scal;
    bf16_t* outb = out + (size_t)img * ((size_t)P * COUT);
    #pragma unroll
    for (int m = 0; m < WMT; ++m) {
        if (pix[m] < P) {
            #pragma unroll
            for (int n = 0; n < NT; ++n) {
                #pragma unroll
                for (int rg = 0; rg < 4; ++rg) {
                    int cb = n * 32 + rg * 8 + h * 4;
                    f32x4 bv = *reinterpret_cast<const f32x4*>(bias + cb);
                    union { bf16x4 v; uint2 u; } o;
                    #pragma unroll
                    for (int j = 0; j < 4; ++j) {
                        float x = acc[m][n][rg * 4 + j] + bv[j];
                        x = x > 0.f ? x : 0.f;
                        x += sc;
                        o.v[j] = (bf16_t)x;
                    }
                    *reinterpret_cast<uint2*>(outb + (size_t)pix[m] * COUT + cb) = o.u;
                }
            }
        }
    }
}

// ---------------------------------------------------------------------------
// Generic implicit-GEMM conv (16x16x32) via global loads — used for conv4c.
// ---------------------------------------------------------------------------
template<int CIN, int COUT, int W, int K, int OW, int NBLK, int WMT,
         int ADD_SCALAR, bool A16>
__global__ __launch_bounds__(256, 2) void conv_mfma(
    const bf16_t* __restrict__ in, const bf16_t* __restrict__ wp,
    const float* __restrict__ bias, bf16_t* __restrict__ out,
    const float* __restrict__ scal) {
    constexpr int P    = OW * OW;
    constexpr int KCIN = K * CIN;
    constexpr int KTOT = K * KCIN;
    constexpr int RS   = KCIN / 32;
    constexpr int NT   = NBLK / 16;
    constexpr int BMT  = WMT * 4;

    const int b     = blockIdx.z;
    const int cout0 = blockIdx.y * NBLK;
    const int wave  = threadIdx.x >> 6;
    const int lane  = threadIdx.x & 63;
    const int l15   = lane & 15;
    const int l4    = lane >> 4;
    const int mt0   = blockIdx.x * BMT + wave * WMT;

    const bf16_t* inb = in + (size_t)b * (W * W * CIN);

    int      pix[WMT];
    uint32_t pb[WMT];
    #pragma unroll
    for (int m = 0; m < WMT; ++m) {
        int p  = (mt0 + m) * 16 + l15;
        pix[m] = p;
        int pc = p < P ? p : P - 1;
        int oh = pc / OW;
        int ow = pc - oh * OW;
        pb[m]  = (uint32_t)(oh * W + ow) * CIN;
    }
    uint32_t wb[NT];
    #pragma unroll
    for (int n = 0; n < NT; ++n)
        wb[n] = (uint32_t)(cout0 + n * 16 + l15) * KTOT + (uint32_t)l4 * 8u;

    f32x4 acc[WMT][NT];
    #pragma unroll
    for (int m = 0; m < WMT; ++m)
        #pragma unroll
        for (int n = 0; n < NT; ++n)
            acc[m][n] = f32x4{0.f, 0.f, 0.f, 0.f};

    uint32_t bofs = (uint32_t)l4 * 8u;
    for (int kh = 0; kh < K; ++kh) {
        #pragma unroll
        for (int s = 0; s < RS; ++s) {
            bf16x8 af[NT];
            #pragma unroll
            for (int n = 0; n < NT; ++n)
                af[n] = load_frag<true>(wp + wb[n] + kh * KCIN + s * 32);
            #pragma unroll
            for (int m = 0; m < WMT; ++m) {
                bf16x8 bfr = load_frag<A16>(inb + pb[m] + bofs + s * 32);
                #pragma unroll
                for (int n = 0; n < NT; ++n)
                    acc[m][n] = mfma16(af[n], bfr, acc[m][n]);
            }
        }
        bofs += (uint32_t)(W * CIN);
    }

    float sc = 0.f;
    if constexpr (ADD_SCALAR) sc = *scal;
    bf16_t* outb = out + (size_t)b * P * COUT;
    #pragma unroll
    for (int n = 0; n < NT; ++n) {
        const int cb = cout0 + n * 16 + l4 * 4;
        f32x4 bv = *reinterpret_cast<const f32x4*>(bias + cb);
        #pragma unroll
        for (int m = 0; m < WMT; ++m) {
            if (pix[m] < P) {
                f32x4 v = acc[m][n];
                union { bf16x4 h; uint2 u; } st;
                #pragma unroll
                for (int r = 0; r < 4; ++r) {
                    float x = v[r] + bv[r];
                    x = x > 0.f ? x : 0.f;
                    x += sc;
                    st.h[r] = (bf16_t)x;
                }
                *reinterpret_cast<uint2*>(outb + (size_t)pix[m] * COUT + cb) = st.u;
            }
        }
    }
}

// ---------------------------------------------------------------------------
// fc2: [128,6400]x[512,6400]^T, K-split x4 into f32 partials.
// ---------------------------------------------------------------------------
__global__ __launch_bounds__(256, 2) void fc2_kernel(
    const bf16_t* __restrict__ x, const bf16_t* __restrict__ w,
    float* __restrict__ part) {
    const int nb = blockIdx.x, kc = blockIdx.y;
    const int wave = threadIdx.x >> 6, lane = threadIdx.x & 63;
    const int l15 = lane & 15, l4 = lane >> 4;
    const int wm = wave & 1, wn = wave >> 1;

    f32x4 acc[4][2];
    #pragma unroll
    for (int m = 0; m < 4; ++m)
        #pragma unroll
        for (int n = 0; n < 2; ++n) acc[m][n] = f32x4{0.f, 0.f, 0.f, 0.f};

    uint32_t xb[4], wbf[2];
    #pragma unroll
    for (int m = 0; m < 4; ++m)
        xb[m] = (uint32_t)(16 * (wm * 4 + m) + l15) * 6400u + kc * 1600u + l4 * 8u;
    #pragma unroll
    for (int n = 0; n < 2; ++n)
        wbf[n] = (uint32_t)(nb * 64 + wn * 32 + n * 16 + l15) * 6400u + kc * 1600u + l4 * 8u;

    for (int s = 0; s < 50; ++s) {
        bf16x8 af[2];
        #pragma unroll
        for (int n = 0; n < 2; ++n)
            af[n] = load_frag<true>(w + wbf[n] + s * 32);
        #pragma unroll
        for (int m = 0; m < 4; ++m) {
            bf16x8 bfr = load_frag<true>(x + xb[m] + s * 32);
            #pragma unroll
            for (int n = 0; n < 2; ++n)
                acc[m][n] = mfma16(af[n], bfr, acc[m][n]);
        }
    }
    #pragma unroll
    for (int m = 0; m < 4; ++m) {
        int bcol = 16 * (wm * 4 + m) + l15;
        #pragma unroll
        for (int n = 0; n < 2; ++n) {
            int cf = nb * 64 + wn * 32 + n * 16 + l4 * 4;
            *reinterpret_cast<f32x4*>(part + ((size_t)kc * 128 + bcol) * 512 + cf) =
                acc[m][n];
        }
    }
}

__global__ void fc2_reduce(const float* __restrict__ part,
                           const float* __restrict__ bias,
                           bf16_t* __restrict__ xo) {
    int t = blockIdx.x * 256 + threadIdx.x;
    if (t < 128 * 512) {
        int b = t >> 9, co = t & 511;
        float s = bias[co];
        #pragma unroll
        for (int kc = 0; kc < 4; ++kc) s += part[((size_t)kc * 128 + b) * 512 + co];
        xo[t] = (bf16_t)(s > 0.f ? s : 0.f);
    }
}

__global__ __launch_bounds__(256, 2) void fc3_kernel(
    const bf16_t* __restrict__ x, const bf16_t* __restrict__ w,
    const float* __restrict__ bias, bf16_t* __restrict__ xo) {
    const int nb = blockIdx.x;
    const int wave = threadIdx.x >> 6, lane = threadIdx.x & 63;
    const int l15 = lane & 15, l4 = lane >> 4;

    f32x4 acc[2][4];
    #pragma unroll
    for (int m = 0; m < 2; ++m)
        #pragma unroll
        for (int n = 0; n < 4; ++n) acc[m][n] = f32x4{0.f, 0.f, 0.f, 0.f};

    uint32_t xb[2], wbf[4];
    #pragma unroll
    for (int m = 0; m < 2; ++m)
        xb[m] = (uint32_t)(16 * (wave * 2 + m) + l15) * 512u + l4 * 8u;
    #pragma unroll
    for (int n = 0; n < 4; ++n)
        wbf[n] = (uint32_t)(nb * 64 + n * 16 + l15) * 512u + l4 * 8u;

    #pragma unroll
    for (int s = 0; s < 16; ++s) {
        bf16x8 af[4];
        #pragma unroll
        for (int n = 0; n < 4; ++n) af[n] = load_frag<true>(w + wbf[n] + s * 32);
        #pragma unroll
        for (int m = 0; m < 2; ++m) {
            bf16x8 bfr = load_frag<true>(x + xb[m] + s * 32);
            #pragma unroll
            for (int n = 0; n < 4; ++n)
                acc[m][n] = mfma16(af[n], bfr, acc[m][n]);
        }
    }
    #pragma unroll
    for (int n = 0; n < 4; ++n) {
        int cf = nb * 64 + n * 16 + l4 * 4;
        f32x4 bv = *reinterpret_cast<const f32x4*>(bias + cf);
        #pragma unroll
        for (int m = 0; m < 2; ++m) {
            int brow = 16 * (wave * 2 + m) + l15;
            union { bf16x4 h; uint2 u; } st;
            #pragma unroll
            for (int r = 0; r < 4; ++r) {
                float v = acc[m][n][r] + bv[r];
                st.h[r] = (bf16_t)(v > 0.f ? v : 0.f);
            }
            *reinterpret_cast<uint2*>(xo + (size_t)brow * 512 + cf) = st.u;
        }
    }
}

__global__ void final_kernel(const bf16_t* __restrict__ x,
                             const float* __restrict__ eaw, const float* __restrict__ eab,
                             const float* __restrict__ evw, const float* __restrict__ evb,
                             float* __restrict__ out) {
    int b = blockIdx.x, lane = threadIdx.x;
    bf16x8 xv = *reinterpret_cast<const bf16x8*>(x + (size_t)b * 512 + lane * 8);
    float xs[8];
    #pragma unroll
    for (int i = 0; i < 8; ++i) xs[i] = (float)xv[i];
    float a[10];
    #pragma unroll
    for (int j = 0; j < 10; ++j) {
        const float* wr = (j < 9) ? (eaw + (size_t)j * 512) : evw;
        const f32x4* w4 = reinterpret_cast<const f32x4*>(wr + lane * 8);
        f32x4 w0 = w4[0], w1 = w4[1];
        float s = 0.f;
        #pragma unroll
        for (int i = 0; i < 4; ++i) s += xs[i] * w0[i];
        #pragma unroll
        for (int i = 0; i < 4; ++i) s += xs[4 + i] * w1[i];
        a[j] = s;
    }
    #pragma unroll
    for (int off = 1; off < 64; off <<= 1)
        #pragma unroll
        for (int j = 0; j < 10; ++j) a[j] += __shfl_xor(a[j], off);
    if (lane < 9) {
        float val  = a[9] + evb[0];
        float mean = 0.f;
        #pragma unroll
        for (int j = 0; j < 9; ++j) mean += a[j] + eab[j];
        mean *= (1.f / 9.f);
        out[b * 9 + lane] = a[lane] + eab[lane] + val - mean;
    }
}

// ---------------------------------------------------------------------------
extern "C" void kernel_launch(void* const* d_in, const int* in_sizes, int n_in,
                              void* d_out, int out_size, void* d_ws, size_t ws_size,
                              hipStream_t stream) {
    const float* state_m  = (const float*)d_in[0];
    const float* state_g  = (const float*)d_in[1];
    const float* state_v  = (const float*)d_in[2];
    const float* conv1_w  = (const float*)d_in[3];
    const float* conv1_b  = (const float*)d_in[4];
    const float* conv2_w  = (const float*)d_in[5];
    const float* conv2_b  = (const float*)d_in[6];
    const float* conv3_w  = (const float*)d_in[7];
    const float* conv3_b  = (const float*)d_in[8];
    const float* conv4_w  = (const float*)d_in[9];
    const float* conv4_b  = (const float*)d_in[10];
    const float* fc1_w    = (const float*)d_in[11];
    const float* fc1_b    = (const float*)d_in[12];
    const float* fc2_w    = (const float*)d_in[13];
    const float* fc2_b    = (const float*)d_in[14];
    const float* fc3_w    = (const float*)d_in[15];
    const float* fc3_b    = (const float*)d_in[16];
    const float* fc4_ea_w = (const float*)d_in[17];
    const float* fc4_ea_b = (const float*)d_in[18];
    const float* fc4_ev_w = (const float*)d_in[19];
    const float* fc4_ev_b = (const float*)d_in[20];

    char* ws = (char*)d_ws;
    // ---- weights & small buffers: [0, 14,418,176) -- never overwritten ----
    bf16_t* w1A    = (bf16_t*)(ws + 0);          //    262,144 conv1 frags
    bf16_t* w2A    = (bf16_t*)(ws + 262144);     //  4,194,304 conv2 frags
    bf16_t* w3A    = (bf16_t*)(ws + 4456448);    //    524,288 conv3 frags
    bf16_t* w4A    = (bf16_t*)(ws + 4980736);    //    524,288 conv4 frags
    bf16_t* w4p    = (bf16_t*)(ws + 5505024);    //    524,288 conv4c generic
    bf16_t* fc2wp  = (bf16_t*)(ws + 6029312);    //  6,553,600
    bf16_t* fc3wp  = (bf16_t*)(ws + 12582912);   //    524,288
    float*  scal   = (float*) (ws + 13107200);   //        256
    float*  part   = (float*) (ws + 13107456);   //  1,048,576
    bf16_t* x2fc   = (bf16_t*)(ws + 14156032);   //    131,072
    bf16_t* x3fc   = (bf16_t*)(ws + 14287104);   //    131,072
    // ---- activations (reuse only where producer strictly after consumer) --
    bf16_t* a0     = (bf16_t*)(ws + 14418176);   // 10,240,000 input NHWC
    bf16_t* x4a    = (bf16_t*)(ws + 14418176);   //  9,437,184 (a0 dead after conv1)
    bf16_t* x1     = (bf16_t*)(ws + 24658176);   // 39,002,112
    bf16_t* x4b    = (bf16_t*)(ws + 24658176);   //  4,734,976 (x1 dead after conv2)
    bf16_t* x4c    = (bf16_t*)(ws + 29393152);   //  1,638,400 (ditto; disjoint from x4b)
    bf16_t* x2     = (bf16_t*)(ws + 63660288);   // 23,658,496
    bf16_t* x3     = (bf16_t*)(ws + 87318784);   // 15,745,024 -> end 103,063,808
    (void)in_sizes; (void)n_in; (void)out_size; (void)ws_size;

    // weight packing + input layout conversion
    pack_wA<4, 32, 32> <<<dim3(64),   256, 0, stream>>>(conv1_w, w1A);
    pack_wA<32, 64, 32><<<dim3(1024), 256, 0, stream>>>(conv2_w, w2A);
    pack_wA<64, 64, 8> <<<dim3(128),  256, 0, stream>>>(conv3_w, w3A);
    pack_wA<64, 64, 8> <<<dim3(128),  256, 0, stream>>>(conv4_w, w4A);
    pack_w<64><<<dim3(16),   256, 0, stream>>>(conv4_w, w4p, 64, 64);
    pack_w<64><<<dim3(200),  256, 0, stream>>>(fc2_w, fc2wp, 512, 100);
    pack_w<1> <<<dim3(1024), 256, 0, stream>>>(fc3_w, fc3wp, 512, 512);
    pack_w<4> <<<dim3(1024), 256, 0, stream>>>(state_m, a0, 128, 10000);
    fc1_scalar<<<1, 64, 0, stream>>>(state_g, state_v, fc1_w, fc1_b, scal);

    // conv chain  conv_rr<CIN,COUT,W,K,OW,WMT,NSLOT,ADD_SCALAR,DEPTH>
    conv_rr<4, 32, 100, 32, 69, 3, 8, 0, 1>
        <<<dim3(13, 1, 128), 256, 0, stream>>>(a0, w1A, conv1_b, x1, nullptr);
    conv_rr<32, 64, 69, 32, 38, 2, 9, 0, 4>       // 768 blocks = 3/CU
        <<<dim3(6, 1, 128), 256, 0, stream>>>(x1, w2A, conv2_b, x2, nullptr);
    conv_rr<64, 64, 38, 8, 31, 2, 11, 1, 1>
        <<<dim3(4, 1, 128), 256, 0, stream>>>(x2, w3A, conv3_b, x3, scal);
    conv_rr<64, 64, 31, 8, 24, 2, 13, 0, 1>
        <<<dim3(3, 1, 128), 256, 0, stream>>>(x3, w4A, conv4_b, x4a, nullptr);
    conv_rr<64, 64, 24, 8, 17, 2, 17, 0, 1>
        <<<dim3(2, 1, 128), 256, 0, stream>>>(x4a, w4A, conv4_b, x4b, nullptr);
    conv_mfma<64, 64, 17, 8, 10, 32, 1, 0, true>
        <<<dim3(2, 2, 128), 256, 0, stream>>>(x4b, w4p, conv4_b, x4c, nullptr);

    // FC head
    fc2_kernel<<<dim3(8, 4), 256, 0, stream>>>(x4c, fc2wp, part);
    fc2_reduce<<<dim3(256), 256, 0, stream>>>(part, fc2_b, x2fc);
    fc3_kernel<<<dim3(8), 256, 0, stream>>>(x2fc, fc3wp, fc3_b, x3fc);
    final_kernel<<<dim3(128), 64, 0, stream>>>(x3fc, fc4_ea_w, fc4_ea_b,
                                               fc4_ev_w, fc4_ev_b, (float*)d_out);
}

// Round 9
// 1145.846 us; speedup vs baseline: 1.3250x; 1.0272x over previous
//
#include <hip/hip_runtime.h>
#include <stdint.h>

// ---------------------------------------------------------------------------
// Dueling-DQN forward on MI355X. Round 9: conv2 gets a dedicated kernel with
// 4-kh fused phases (barriers 32 -> 8, NSLOT=16 row ring, 73 KB LDS) around
// the proven WMT=3 4-deep register pipeline. Other kernels = round 8.
// ---------------------------------------------------------------------------

using bf16_t = __bf16;
using bf16x8 = __attribute__((ext_vector_type(8))) __bf16;
using bf16x4 = __attribute__((ext_vector_type(4))) __bf16;
using f32x4  = __attribute__((ext_vector_type(4))) float;
using f32x16 = __attribute__((ext_vector_type(16))) float;

__device__ __forceinline__ f32x4 mfma16(bf16x8 a, bf16x8 b, f32x4 c) {
    return __builtin_amdgcn_mfma_f32_16x16x32_bf16(a, b, c, 0, 0, 0);
}
__device__ __forceinline__ f32x16 mfma32(bf16x8 a, bf16x8 b, f32x16 c) {
    return __builtin_amdgcn_mfma_f32_32x32x16_bf16(a, b, c, 0, 0, 0);
}

template<bool A16>
__device__ __forceinline__ bf16x8 load_frag(const bf16_t* p) {
    if constexpr (A16) {
        return *reinterpret_cast<const bf16x8*>(p);
    } else {
        union { bf16x8 v; uint64_t u[2]; } r;
        r.u[0] = *reinterpret_cast<const uint64_t*>(p);
        r.u[1] = *reinterpret_cast<const uint64_t*>(p + 4);
        return r.v;
    }
}

// ---------------------------------------------------------------------------
// Generic pack: dst[cout][khw][cin] = (bf16)src[cout][cin][khw]
// ---------------------------------------------------------------------------
template<int CIN>
__global__ void pack_w(const float* __restrict__ src, bf16_t* __restrict__ dst,
                       int COUT, int KK) {
    int total = COUT * KK;
    for (int t = blockIdx.x * blockDim.x + threadIdx.x; t < total;
         t += gridDim.x * blockDim.x) {
        int cout = t / KK;
        int khw  = t - cout * KK;
        alignas(16) bf16_t tmp[CIN];
        #pragma unroll
        for (int c = 0; c < CIN; ++c)
            tmp[c] = (bf16_t)src[((size_t)cout * CIN + c) * KK + khw];
        bf16_t* d = dst + (size_t)t * CIN;
        if constexpr (CIN == 1) {
            d[0] = tmp[0];
        } else if constexpr (CIN == 4) {
            *reinterpret_cast<uint2*>(d) = *reinterpret_cast<const uint2*>(tmp);
        } else {
            #pragma unroll
            for (int c = 0; c < CIN; c += 8)
                *reinterpret_cast<uint4*>(d + c) =
                    *reinterpret_cast<const uint4*>(tmp + c);
        }
    }
}

// ---------------------------------------------------------------------------
// A-fragment pack for 32x32x16 MFMA conv: frag f = (kh*S + s)*NT + n holds
// couts n*32+(l&31); k = s*16 + (l>>5)*8 + e; k -> (kw = k/CIN, cin = k%CIN).
// ---------------------------------------------------------------------------
template<int CIN, int COUT, int K>
__global__ void pack_wA(const float* __restrict__ src, bf16_t* __restrict__ dst) {
    constexpr int S  = K * CIN / 16;
    constexpr int NT = COUT / 32;
    int t = blockIdx.x * 256 + threadIdx.x;
    int l  = t & 63;
    int f  = t >> 6;
    int n  = f % NT;
    int fs = f / NT;
    int s  = fs % S;
    int kh = fs / S;
    if (kh >= K) return;
    int cout = n * 32 + (l & 31);
    int k0   = s * 16 + (l >> 5) * 8;
    alignas(16) bf16_t tmp[8];
    #pragma unroll
    for (int e = 0; e < 8; ++e) {
        int k   = k0 + e;
        int kw  = k / CIN;
        int cin = k % CIN;
        tmp[e] = (bf16_t)src[(((size_t)cout * CIN + cin) * K + kh) * K + kw];
    }
    *reinterpret_cast<uint4*>(dst + (size_t)t * 8) =
        *reinterpret_cast<const uint4*>(tmp);
}

// scalar = relu(fc1(concat(g[0],v[0]))[30])
__global__ void fc1_scalar(const float* __restrict__ g, const float* __restrict__ v,
                           const float* __restrict__ w, const float* __restrict__ b,
                           float* __restrict__ outp) {
    if (threadIdx.x == 0 && blockIdx.x == 0) {
        float s = b[30] + g[0] * w[120] + g[1] * w[121] + v[0] * w[122] + v[1] * w[123];
        *outp = s > 0.f ? s : 0.f;
    }
}

// ---------------------------------------------------------------------------
// conv2 dedicated: CIN=32, W=69, K=32, OW=38. WMT=3, 4 waves, BPX=384.
// 4-kh fused phases: NSLOT=16 row ring (slot = row mod 16), one barrier per
// 4 kh. 4-deep register pipeline, setprio, deferred 4-row prefetch.
// ---------------------------------------------------------------------------
__global__ __launch_bounds__(256, 2) void conv2_k4(
    const bf16_t* __restrict__ in, const bf16_t* __restrict__ wA,
    const float* __restrict__ bias, bf16_t* __restrict__ out) {
    constexpr int W = 69, OW = 38, CIN = 32;
    constexpr int P    = OW * OW;          // 1444
    constexpr int ROWB = W * CIN * 2;      // 4416
    constexpr int PS   = (W + 1) * 16;     // 1120 plane stride
    constexpr int SLOTB = 4576;            // 4*PS + 96 pad (bank-stagger)
    constexpr int NSLOT = 16;
    constexpr int LDSB  = NSLOT * SLOTB;   // 73216
    constexpr int S = 64, NT = 2, WMT = 3;
    constexpr int BPX = 384;
    constexpr int CHR = ROWB / 16;         // 276 16B units per row
    constexpr int CH4 = 4 * CHR;           // 1104
    __shared__ __align__(16) char smem[LDSB];

    const int tid  = threadIdx.x;
    const int wave = tid >> 6, lane = tid & 63;
    const int l31  = lane & 31, h = lane >> 5;
    const int img  = blockIdx.z;
    const int p0   = blockIdx.x * BPX;

    const char* inb = (const char*)(in + (size_t)img * (W * W * CIN));
    const int r0 = p0 / OW;
    int plast = p0 + BPX - 1; if (plast > P - 1) plast = P - 1;
    const int r1 = plast / OW;

    int pix[WMT], ldsadr[WMT];
    #pragma unroll
    for (int m = 0; m < WMT; ++m) {
        int p  = p0 + (wave * WMT + m) * 32 + l31;
        pix[m] = p;
        int pc = p < P ? p : P - 1;
        int oh = pc / OW;
        int ow = pc - oh * OW;
        ldsadr[m] = (oh & 15) * SLOTB + ow * 16 + h * PS;
    }

    // prologue: rows r0 .. r1+3, slot = row mod 16, TR chunk-plane layout
    for (int r = r0; r <= r1 + 3; ++r) {
        const char* g = inb + (size_t)r * ROWB;
        int base = (r & 15) * SLOTB;
        for (int c = tid; c < CHR; c += 256)
            *reinterpret_cast<bf16x8*>(smem + base + (c & 3) * PS + (c >> 2) * 16) =
                *reinterpret_cast<const bf16x8*>(g + c * 16);
    }
    __syncthreads();

    f32x16 acc[WMT][NT] = {};
    int wsl = (r1 + 4) & 15;
    const char* gpre = inb + (size_t)(r1 + 4) * ROWB;
    const bf16_t* wl = wA + lane * 8;

    for (int kp = 0; kp < 8; ++kp) {
        const bool pf = kp < 7;
        bf16x8 stv[5];

#define STVISSUE                                                            \
        if (pf) {                                                           \
            _Pragma("unroll")                                               \
            for (int i = 0; i < 5; ++i) {                                   \
                int c = i * 256 + tid;                                      \
                if (c < CH4) stv[i] = *reinterpret_cast<const bf16x8*>(gpre + c * 16); \
            }                                                               \
        }

        #pragma unroll
        for (int kl = 0; kl < 4; ++kl) {
            const bf16_t* ap = wl + (size_t)(kp * 4 + kl) * (S * NT * 512);
            int adr[WMT];
            #pragma unroll
            for (int m = 0; m < WMT; ++m) {
                int a = ldsadr[m] + kl * SLOTB;
                adr[m] = a >= LDSB ? a - LDSB : a;
            }

            bf16x8 bS0[WMT], bS1[WMT], bS2[WMT], bS3[WMT];
            bf16x8 aS0[NT],  aS1[NT],  aS2[NT],  aS3[NT];

#define LOADSET(BS, AS, SIDX)                                               \
            {                                                               \
                const int _s = (SIDX);                                      \
                _Pragma("unroll")                                           \
                for (int m = 0; m < WMT; ++m)                               \
                    BS[m] = *reinterpret_cast<const bf16x8*>(                \
                        smem + adr[m] + (_s & 1) * (2 * PS) + (_s >> 1) * 16); \
                _Pragma("unroll")                                           \
                for (int n = 0; n < NT; ++n)                                \
                    AS[n] = *reinterpret_cast<const bf16x8*>(ap + (_s * NT + n) * 512); \
            }
#define MFMASET(BS, AS)                                                     \
            {                                                               \
                __builtin_amdgcn_s_setprio(1);                              \
                _Pragma("unroll")                                           \
                for (int m = 0; m < WMT; ++m)                               \
                    _Pragma("unroll")                                       \
                    for (int n = 0; n < NT; ++n)                            \
                        acc[m][n] = mfma32(AS[n], BS[m], acc[m][n]);        \
                __builtin_amdgcn_s_setprio(0);                              \
            }

            LOADSET(bS0, aS0, 0)
            LOADSET(bS1, aS1, 1)
            LOADSET(bS2, aS2, 2)
            MFMASET(bS0, aS0)  LOADSET(bS3, aS3, 3)
            MFMASET(bS1, aS1)  LOADSET(bS0, aS0, 4)
            MFMASET(bS2, aS2)  LOADSET(bS1, aS1, 5)
            MFMASET(bS3, aS3)  LOADSET(bS2, aS2, 6)
            if (kl == 0) { STVISSUE }     // deferred: 7 LOADSETs already queued
            for (int sb = 4; sb + 8 <= S; sb += 4) {
                MFMASET(bS0, aS0)  LOADSET(bS3, aS3, sb + 3)
                MFMASET(bS1, aS1)  LOADSET(bS0, aS0, sb + 4)
                MFMASET(bS2, aS2)  LOADSET(bS1, aS1, sb + 5)
                MFMASET(bS3, aS3)  LOADSET(bS2, aS2, sb + 6)
            }
            MFMASET(bS0, aS0)  LOADSET(bS3, aS3, S - 1)
            MFMASET(bS1, aS1)
            MFMASET(bS2, aS2)
            MFMASET(bS3, aS3)
#undef LOADSET
#undef MFMASET
        }
#undef STVISSUE

        if (pf) {                                    // write-late: 4 rows
            #pragma unroll
            for (int i = 0; i < 5; ++i) {
                int c = i * 256 + tid;
                if (c < CH4) {
                    int j = c / CHR, u = c - j * CHR;
                    *reinterpret_cast<bf16x8*>(
                        smem + ((wsl + j) & 15) * SLOTB + (u & 3) * PS + (u >> 2) * 16) = stv[i];
                }
            }
            gpre += 4 * ROWB;
            wsl = (wsl + 4) & 15;
        }
        __syncthreads();
        #pragma unroll
        for (int m = 0; m < WMT; ++m) {
            int a2 = ldsadr[m] + 4 * SLOTB;
            ldsadr[m] = a2 >= LDSB ? a2 - LDSB : a2;
        }
    }

    bf16_t* outb = out + (size_t)img * ((size_t)P * 64);
    #pragma unroll
    for (int m = 0; m < WMT; ++m) {
        if (pix[m] < P) {
            #pragma unroll
            for (int n = 0; n < NT; ++n) {
                #pragma unroll
                for (int rg = 0; rg < 4; ++rg) {
                    int cb = n * 32 + rg * 8 + h * 4;
                    f32x4 bv = *reinterpret_cast<const f32x4*>(bias + cb);
                    union { bf16x4 v; uint2 u; } o;
                    #pragma unroll
                    for (int j = 0; j < 4; ++j) {
                        float x = acc[m][n][rg * 4 + j] + bv[j];
                        o.v[j] = (bf16_t)(x > 0.f ? x : 0.f);
                    }
                    *reinterpret_cast<uint2*>(outb + (size_t)pix[m] * 64 + cb) = o.u;
                }
            }
        }
    }
}

// ---------------------------------------------------------------------------
// Rolling-row LDS implicit-GEMM conv (round-8 form) — conv1/conv3/conv4a/b.
// ---------------------------------------------------------------------------
template<int CIN, int COUT, int W, int K, int OW, int WMT, int NSLOT,
         int ADD_SCALAR>
__global__ __launch_bounds__(256, 2) void conv_rr(
    const bf16_t* __restrict__ in, const bf16_t* __restrict__ wA,
    const float* __restrict__ bias, bf16_t* __restrict__ out,
    const float* __restrict__ scal) {
    constexpr int  P     = OW * OW;
    constexpr int  PIXB  = CIN * 2;
    constexpr int  ROWB  = W * PIXB;
    constexpr bool TR    = (CIN >= 16);
    constexpr int  NCH   = TR ? PIXB / 16 : 1;
    constexpr int  SPP   = TR ? NCH / 2 : 1;
    constexpr int  PS    = TR ? (W + 1) * 16 : 0;
    constexpr int  SLOTB0 = TR ? NCH * PS : ROWB;
    constexpr int  PADB  = TR ? ((16 * OW - SLOTB0) % 128 + 128) % 128 : 0;
    constexpr int  SLOTB = SLOTB0 + PADB;
    constexpr int  LDSB  = NSLOT * SLOTB;
    constexpr int  S     = K * CIN / 16;
    constexpr int  NT    = COUT / 32;
    constexpr int  BPX   = WMT * 32 * 4;
    constexpr int  CH    = ROWB / 16;
    constexpr int  NLD   = (CH + 255) / 256;
    __shared__ __align__(16) char smem[LDSB];

    const int tid  = threadIdx.x;
    const int wave = tid >> 6, lane = tid & 63;
    const int l31  = lane & 31, h = lane >> 5;
    const int img  = blockIdx.z;
    const int p0   = blockIdx.x * BPX;

    const char* inb = (const char*)(in + (size_t)img * ((size_t)W * W * CIN));

    const int r0 = p0 / OW;
    int plast = p0 + BPX - 1; if (plast > P - 1) plast = P - 1;
    const int r1 = plast / OW;

    int woff[NLD];
    #pragma unroll
    for (int i = 0; i < NLD; ++i) {
        int c = i * 256 + tid;
        if (c < CH) woff[i] = TR ? (c % NCH) * PS + (c / NCH) * 16 : c * 16;
        else        woff[i] = 0;
    }

    int pix[WMT], ldsadr[WMT];
    #pragma unroll
    for (int m = 0; m < WMT; ++m) {
        int p  = p0 + (wave * WMT + m) * 32 + l31;
        pix[m] = p;
        int pc = p < P ? p : P - 1;
        int oh = pc / OW;
        int ow = pc - oh * OW;
        ldsadr[m] = (oh % NSLOT) * SLOTB +
                    (TR ? ow * 16 + h * PS : ow * PIXB + h * 16);
    }

    for (int r = r0; r <= r1; ++r) {
        const char* g = inb + (size_t)r * ROWB;
        int base = (r % NSLOT) * SLOTB;
        for (int c = tid; c < CH; c += 256) {
            bf16x8 v = *reinterpret_cast<const bf16x8*>(g + c * 16);
            int off = TR ? (c % NCH) * PS + (c / NCH) * 16 : c * 16;
            *reinterpret_cast<bf16x8*>(smem + base + off) = v;
        }
    }
    __syncthreads();

    f32x16 acc[WMT][NT] = {};

    int wsl = (r1 + 1) % NSLOT;
    const char* gpre = inb + (size_t)(r1 + 1) * ROWB;
    const bf16_t* wl = wA + lane * 8;

    for (int kh = 0; kh < K; ++kh) {
        bf16x8 stv[NLD];
        const bool pf = kh < K - 1;
        const bf16_t* ap = wl + (size_t)kh * (S * NT * 512);

        auto bread = [&](int m, int s) -> bf16x8 {
            int a = TR ? ldsadr[m] + (s % SPP) * (2 * PS) + (s / SPP) * 16
                       : ldsadr[m] + s * 32;
            return *reinterpret_cast<const bf16x8*>(smem + a);
        };
        bf16x8 bcur[WMT], acur[NT];
        #pragma unroll
        for (int m = 0; m < WMT; ++m) bcur[m] = bread(m, 0);
        #pragma unroll
        for (int n = 0; n < NT; ++n)
            acur[n] = *reinterpret_cast<const bf16x8*>(ap + n * 512);

        #pragma unroll
        for (int s = 0; s < S - 1; ++s) {
            bf16x8 bnx[WMT], anx[NT];
            #pragma unroll
            for (int m = 0; m < WMT; ++m) bnx[m] = bread(m, s + 1);
            #pragma unroll
            for (int n = 0; n < NT; ++n)
                anx[n] = *reinterpret_cast<const bf16x8*>(ap + ((s + 1) * NT + n) * 512);
            if (s == 2 && pf) {
                #pragma unroll
                for (int i = 0; i < NLD; ++i) {
                    int c = i * 256 + tid;
                    if (c < CH) stv[i] = *reinterpret_cast<const bf16x8*>(gpre + c * 16);
                }
            }
            #pragma unroll
            for (int m = 0; m < WMT; ++m)
                #pragma unroll
                for (int n = 0; n < NT; ++n)
                    acc[m][n] = mfma32(acur[n], bcur[m], acc[m][n]);
            #pragma unroll
            for (int m = 0; m < WMT; ++m) bcur[m] = bnx[m];
            #pragma unroll
            for (int n = 0; n < NT; ++n) acur[n] = anx[n];
        }
        #pragma unroll
        for (int m = 0; m < WMT; ++m)
            #pragma unroll
            for (int n = 0; n < NT; ++n)
                acc[m][n] = mfma32(acur[n], bcur[m], acc[m][n]);

        if (pf) {
            int wb0 = wsl * SLOTB;
            #pragma unroll
            for (int i = 0; i < NLD; ++i) {
                int c = i * 256 + tid;
                if (c < CH)
                    *reinterpret_cast<bf16x8*>(smem + wb0 + woff[i]) = stv[i];
            }
            gpre += ROWB;
            wsl = (wsl + 1 == NSLOT) ? 0 : wsl + 1;
        }
        __syncthreads();
        #pragma unroll
        for (int m = 0; m < WMT; ++m) {
            int a2 = ldsadr[m] + SLOTB;
            ldsadr[m] = a2 >= LDSB ? a2 - LDSB : a2;
        }
    }

    float sc = 0.f;
    if constexpr (ADD_SCALAR) sc = *scal;
    bf16_t* outb = out + (size_t)img * ((size_t)P * COUT);
    #pragma unroll
    for (int m = 0; m < WMT; ++m) {
        if (pix[m] < P) {
            #pragma unroll
            for (int n = 0; n < NT; ++n) {
                #pragma unroll
                for (int rg = 0; rg < 4; ++rg) {
                    int cb = n * 32 + rg * 8 + h * 4;
                    f32x4 bv = *reinterpret_cast<const f32x4*>(bias + cb);
                    union { bf16x4 v; uint2 u; } o;
                    #pragma unroll
                    for (int j = 0; j < 4; ++j) {
                        float x = acc[m][n][rg * 4 + j] + bv[j];
                        x = x > 0.f ? x : 0.f;
                        x += sc;
                        o.v[j] = (bf16_t)x;
                    }
                    *reinterpret_cast<uint2*>(outb + (size_t)pix[m] * COUT + cb) = o.u;
                }
            }
        }
    }
}

// ---------------------------------------------------------------------------
// Generic implicit-GEMM conv (16x16x32) via global loads — used for conv4c.
// ---------------------------------------------------------------------------
template<int CIN, int COUT, int W, int K, int OW, int NBLK, int WMT,
         int ADD_SCALAR, bool A16>
__global__ __launch_bounds__(256, 2) void conv_mfma(
    const bf16_t* __restrict__ in, const bf16_t* __restrict__ wp,
    const float* __restrict__ bias, bf16_t* __restrict__ out,
    const float* __restrict__ scal) {
    constexpr int P    = OW * OW;
    constexpr int KCIN = K * CIN;
    constexpr int KTOT = K * KCIN;
    constexpr int RS   = KCIN / 32;
    constexpr int NT   = NBLK / 16;
    constexpr int BMT  = WMT * 4;

    const int b     = blockIdx.z;
    const int cout0 = blockIdx.y * NBLK;
    const int wave  = threadIdx.x >> 6;
    const int lane  = threadIdx.x & 63;
    const int l15   = lane & 15;
    const int l4    = lane >> 4;
    const int mt0   = blockIdx.x * BMT + wave * WMT;

    const bf16_t* inb = in + (size_t)b * (W * W * CIN);

    int      pix[WMT];
    uint32_t pb[WMT];
    #pragma unroll
    for (int m = 0; m < WMT; ++m) {
        int p  = (mt0 + m) * 16 + l15;
        pix[m] = p;
        int pc = p < P ? p : P - 1;
        int oh = pc / OW;
        int ow = pc - oh * OW;
        pb[m]  = (uint32_t)(oh * W + ow) * CIN;
    }
    uint32_t wb[NT];
    #pragma unroll
    for (int n = 0; n < NT; ++n)
        wb[n] = (uint32_t)(cout0 + n * 16 + l15) * KTOT + (uint32_t)l4 * 8u;

    f32x4 acc[WMT][NT];
    #pragma unroll
    for (int m = 0; m < WMT; ++m)
        #pragma unroll
        for (int n = 0; n < NT; ++n)
            acc[m][n] = f32x4{0.f, 0.f, 0.f, 0.f};

    uint32_t bofs = (uint32_t)l4 * 8u;
    for (int kh = 0; kh < K; ++kh) {
        #pragma unroll
        for (int s = 0; s < RS; ++s) {
            bf16x8 af[NT];
            #pragma unroll
            for (int n = 0; n < NT; ++n)
                af[n] = load_frag<true>(wp + wb[n] + kh * KCIN + s * 32);
            #pragma unroll
            for (int m = 0; m < WMT; ++m) {
                bf16x8 bfr = load_frag<A16>(inb + pb[m] + bofs + s * 32);
                #pragma unroll
                for (int n = 0; n < NT; ++n)
                    acc[m][n] = mfma16(af[n], bfr, acc[m][n]);
            }
        }
        bofs += (uint32_t)(W * CIN);
    }

    float sc = 0.f;
    if constexpr (ADD_SCALAR) sc = *scal;
    bf16_t* outb = out + (size_t)b * P * COUT;
    #pragma unroll
    for (int n = 0; n < NT; ++n) {
        const int cb = cout0 + n * 16 + l4 * 4;
        f32x4 bv = *reinterpret_cast<const f32x4*>(bias + cb);
        #pragma unroll
        for (int m = 0; m < WMT; ++m) {
            if (pix[m] < P) {
                f32x4 v = acc[m][n];
                union { bf16x4 h; uint2 u; } st;
                #pragma unroll
                for (int r = 0; r < 4; ++r) {
                    float x = v[r] + bv[r];
                    x = x > 0.f ? x : 0.f;
                    x += sc;
                    st.h[r] = (bf16_t)x;
                }
                *reinterpret_cast<uint2*>(outb + (size_t)pix[m] * COUT + cb) = st.u;
            }
        }
    }
}

// ---------------------------------------------------------------------------
// fc2: [128,6400]x[512,6400]^T, K-split x4 into f32 partials.
// ---------------------------------------------------------------------------
__global__ __launch_bounds__(256, 2) void fc2_kernel(
    const bf16_t* __restrict__ x, const bf16_t* __restrict__ w,
    float* __restrict__ part) {
    const int nb = blockIdx.x, kc = blockIdx.y;
    const int wave = threadIdx.x >> 6, lane = threadIdx.x & 63;
    const int l15 = lane & 15, l4 = lane >> 4;
    const int wm = wave & 1, wn = wave >> 1;

    f32x4 acc[4][2];
    #pragma unroll
    for (int m = 0; m < 4; ++m)
        #pragma unroll
        for (int n = 0; n < 2; ++n) acc[m][n] = f32x4{0.f, 0.f, 0.f, 0.f};

    uint32_t xb[4], wbf[2];
    #pragma unroll
    for (int m = 0; m < 4; ++m)
        xb[m] = (uint32_t)(16 * (wm * 4 + m) + l15) * 6400u + kc * 1600u + l4 * 8u;
    #pragma unroll
    for (int n = 0; n < 2; ++n)
        wbf[n] = (uint32_t)(nb * 64 + wn * 32 + n * 16 + l15) * 6400u + kc * 1600u + l4 * 8u;

    for (int s = 0; s < 50; ++s) {
        bf16x8 af[2];
        #pragma unroll
        for (int n = 0; n < 2; ++n)
            af[n] = load_frag<true>(w + wbf[n] + s * 32);
        #pragma unroll
        for (int m = 0; m < 4; ++m) {
            bf16x8 bfr = load_frag<true>(x + xb[m] + s * 32);
            #pragma unroll
            for (int n = 0; n < 2; ++n)
                acc[m][n] = mfma16(af[n], bfr, acc[m][n]);
        }
    }
    #pragma unroll
    for (int m = 0; m < 4; ++m) {
        int bcol = 16 * (wm * 4 + m) + l15;
        #pragma unroll
        for (int n = 0; n < 2; ++n) {
            int cf = nb * 64 + wn * 32 + n * 16 + l4 * 4;
            *reinterpret_cast<f32x4*>(part + ((size_t)kc * 128 + bcol) * 512 + cf) =
                acc[m][n];
        }
    }
}

__global__ void fc2_reduce(const float* __restrict__ part,
                           const float* __restrict__ bias,
                           bf16_t* __restrict__ xo) {
    int t = blockIdx.x * 256 + threadIdx.x;
    if (t < 128 * 512) {
        int b = t >> 9, co = t & 511;
        float s = bias[co];
        #pragma unroll
        for (int kc = 0; kc < 4; ++kc) s += part[((size_t)kc * 128 + b) * 512 + co];
        xo[t] = (bf16_t)(s > 0.f ? s : 0.f);
    }
}

__global__ __launch_bounds__(256, 2) void fc3_kernel(
    const bf16_t* __restrict__ x, const bf16_t* __restrict__ w,
    const float* __restrict__ bias, bf16_t* __restrict__ xo) {
    const int nb = blockIdx.x;
    const int wave = threadIdx.x >> 6, lane = threadIdx.x & 63;
    const int l15 = lane & 15, l4 = lane >> 4;

    f32x4 acc[2][4];
    #pragma unroll
    for (int m = 0; m < 2; ++m)
        #pragma unroll
        for (int n = 0; n < 4; ++n) acc[m][n] = f32x4{0.f, 0.f, 0.f, 0.f};

    uint32_t xb[2], wbf[4];
    #pragma unroll
    for (int m = 0; m < 2; ++m)
        xb[m] = (uint32_t)(16 * (wave * 2 + m) + l15) * 512u + l4 * 8u;
    #pragma unroll
    for (int n = 0; n < 4; ++n)
        wbf[n] = (uint32_t)(nb * 64 + n * 16 + l15) * 512u + l4 * 8u;

    #pragma unroll
    for (int s = 0; s < 16; ++s) {
        bf16x8 af[4];
        #pragma unroll
        for (int n = 0; n < 4; ++n) af[n] = load_frag<true>(w + wbf[n] + s * 32);
        #pragma unroll
        for (int m = 0; m < 2; ++m) {
            bf16x8 bfr = load_frag<true>(x + xb[m] + s * 32);
            #pragma unroll
            for (int n = 0; n < 4; ++n)
                acc[m][n] = mfma16(af[n], bfr, acc[m][n]);
        }
    }
    #pragma unroll
    for (int n = 0; n < 4; ++n) {
        int cf = nb * 64 + n * 16 + l4 * 4;
        f32x4 bv = *reinterpret_cast<const f32x4*>(bias + cf);
        #pragma unroll
        for (int m = 0; m < 2; ++m) {
            int brow = 16 * (wave * 2 + m) + l15;
            union { bf16x4 h; uint2 u; } st;
            #pragma unroll
            for (int r = 0; r < 4; ++r) {
                float v = acc[m][n][r] + bv[r];
                st.h[r] = (bf16_t)(v > 0.f ? v : 0.f);
            }
            *reinterpret_cast<uint2*>(xo + (size_t)brow * 512 + cf) = st.u;
        }
    }
}

__global__ void final_kernel(const bf16_t* __restrict__ x,
                             const float* __restrict__ eaw, const float* __restrict__ eab,
                             const float* __restrict__ evw, const float* __restrict__ evb,
                             float* __restrict__ out) {
    int b = blockIdx.x, lane = threadIdx.x;
    bf16x8 xv = *reinterpret_cast<const bf16x8*>(x + (size_t)b * 512 + lane * 8);
    float xs[8];
    #pragma unroll
    for (int i = 0; i < 8; ++i) xs[i] = (float)xv[i];
    float a[10];
    #pragma unroll
    for (int j = 0; j < 10; ++j) {
        const float* wr = (j < 9) ? (eaw + (size_t)j * 512) : evw;
        const f32x4* w4 = reinterpret_cast<const f32x4*>(wr + lane * 8);
        f32x4 w0 = w4[0], w1 = w4[1];
        float s = 0.f;
        #pragma unroll
        for (int i = 0; i < 4; ++i) s += xs[i] * w0[i];
        #pragma unroll
        for (int i = 0; i < 4; ++i) s += xs[4 + i] * w1[i];
        a[j] = s;
    }
    #pragma unroll
    for (int off = 1; off < 64; off <<= 1)
        #pragma unroll
        for (int j = 0; j < 10; ++j) a[j] += __shfl_xor(a[j], off);
    if (lane < 9) {
        float val  = a[9] + evb[0];
        float mean = 0.f;
        #pragma unroll
        for (int j = 0; j < 9; ++j) mean += a[j] + eab[j];
        mean *= (1.f / 9.f);
        out[b * 9 + lane] = a[lane] + eab[lane] + val - mean;
    }
}

// ---------------------------------------------------------------------------
extern "C" void kernel_launch(void* const* d_in, const int* in_sizes, int n_in,
                              void* d_out, int out_size, void* d_ws, size_t ws_size,
                              hipStream_t stream) {
    const float* state_m  = (const float*)d_in[0];
    const float* state_g  = (const float*)d_in[1];
    const float* state_v  = (const float*)d_in[2];
    const float* conv1_w  = (const float*)d_in[3];
    const float* conv1_b  = (const float*)d_in[4];
    const float* conv2_w  = (const float*)d_in[5];
    const float* conv2_b  = (const float*)d_in[6];
    const float* conv3_w  = (const float*)d_in[7];
    const float* conv3_b  = (const float*)d_in[8];
    const float* conv4_w  = (const float*)d_in[9];
    const float* conv4_b  = (const float*)d_in[10];
    const float* fc1_w    = (const float*)d_in[11];
    const float* fc1_b    = (const float*)d_in[12];
    const float* fc2_w    = (const float*)d_in[13];
    const float* fc2_b    = (const float*)d_in[14];
    const float* fc3_w    = (const float*)d_in[15];
    const float* fc3_b    = (const float*)d_in[16];
    const float* fc4_ea_w = (const float*)d_in[17];
    const float* fc4_ea_b = (const float*)d_in[18];
    const float* fc4_ev_w = (const float*)d_in[19];
    const float* fc4_ev_b = (const float*)d_in[20];

    char* ws = (char*)d_ws;
    // ---- weights & small buffers: [0, 14,418,176) -- never overwritten ----
    bf16_t* w1A    = (bf16_t*)(ws + 0);          //    262,144 conv1 frags
    bf16_t* w2A    = (bf16_t*)(ws + 262144);     //  4,194,304 conv2 frags
    bf16_t* w3A    = (bf16_t*)(ws + 4456448);    //    524,288 conv3 frags
    bf16_t* w4A    = (bf16_t*)(ws + 4980736);    //    524,288 conv4 frags
    bf16_t* w4p    = (bf16_t*)(ws + 5505024);    //    524,288 conv4c generic
    bf16_t* fc2wp  = (bf16_t*)(ws + 6029312);    //  6,553,600
    bf16_t* fc3wp  = (bf16_t*)(ws + 12582912);   //    524,288
    float*  scal   = (float*) (ws + 13107200);   //        256
    float*  part   = (float*) (ws + 13107456);   //  1,048,576
    bf16_t* x2fc   = (bf16_t*)(ws + 14156032);   //    131,072
    bf16_t* x3fc   = (bf16_t*)(ws + 14287104);   //    131,072
    // ---- activations (reuse only where producer strictly after consumer) --
    bf16_t* a0     = (bf16_t*)(ws + 14418176);   // 10,240,000 input NHWC
    bf16_t* x4a    = (bf16_t*)(ws + 14418176);   //  9,437,184 (a0 dead after conv1)
    bf16_t* x1     = (bf16_t*)(ws + 24658176);   // 39,002,112
    bf16_t* x4b    = (bf16_t*)(ws + 24658176);   //  4,734,976 (x1 dead after conv2)
    bf16_t* x4c    = (bf16_t*)(ws + 29393152);   //  1,638,400 (ditto; disjoint from x4b)
    bf16_t* x2     = (bf16_t*)(ws + 63660288);   // 23,658,496
    bf16_t* x3     = (bf16_t*)(ws + 87318784);   // 15,745,024 -> end 103,063,808
    (void)in_sizes; (void)n_in; (void)out_size; (void)ws_size;

    // weight packing + input layout conversion
    pack_wA<4, 32, 32> <<<dim3(64),   256, 0, stream>>>(conv1_w, w1A);
    pack_wA<32, 64, 32><<<dim3(1024), 256, 0, stream>>>(conv2_w, w2A);
    pack_wA<64, 64, 8> <<<dim3(128),  256, 0, stream>>>(conv3_w, w3A);
    pack_wA<64, 64, 8> <<<dim3(128),  256, 0, stream>>>(conv4_w, w4A);
    pack_w<64><<<dim3(16),   256, 0, stream>>>(conv4_w, w4p, 64, 64);
    pack_w<64><<<dim3(200),  256, 0, stream>>>(fc2_w, fc2wp, 512, 100);
    pack_w<1> <<<dim3(1024), 256, 0, stream>>>(fc3_w, fc3wp, 512, 512);
    pack_w<4> <<<dim3(1024), 256, 0, stream>>>(state_m, a0, 128, 10000);
    fc1_scalar<<<1, 64, 0, stream>>>(state_g, state_v, fc1_w, fc1_b, scal);

    // conv chain
    conv_rr<4, 32, 100, 32, 69, 3, 8, 0>
        <<<dim3(13, 1, 128), 256, 0, stream>>>(a0, w1A, conv1_b, x1, nullptr);
    conv2_k4<<<dim3(4, 1, 128), 256, 0, stream>>>(x1, w2A, conv2_b, x2);
    conv_rr<64, 64, 38, 8, 31, 2, 11, 1>
        <<<dim3(4, 1, 128), 256, 0, stream>>>(x2, w3A, conv3_b, x3, scal);
    conv_rr<64, 64, 31, 8, 24, 2, 13, 0>
        <<<dim3(3, 1, 128), 256, 0, stream>>>(x3, w4A, conv4_b, x4a, nullptr);
    conv_rr<64, 64, 24, 8, 17, 2, 17, 0>
        <<<dim3(2, 1, 128), 256, 0, stream>>>(x4a, w4A, conv4_b, x4b, nullptr);
    conv_mfma<64, 64, 17, 8, 10, 32, 1, 0, true>
        <<<dim3(2, 2, 128), 256, 0, stream>>>(x4b, w4p, conv4_b, x4c, nullptr);

    // FC head
    fc2_kernel<<<dim3(8, 4), 256, 0, stream>>>(x4c, fc2wp, part);
    fc2_reduce<<<dim3(256), 256, 0, stream>>>(part, fc2_b, x2fc);
    fc3_kernel<<<dim3(8), 256, 0, stream>>>(x2fc, fc3wp, fc3_b, x3fc);
    final_kernel<<<dim3(128), 64, 0, stream>>>(x3fc, fc4_ea_w, fc4_ea_b,
                                               fc4_ev_w, fc4_ev_b, (float*)d_out);
}